// Round 12
// baseline (570.473 us; speedup 1.0000x reference)
//
#include <hip/hip_runtime.h>
#include <math.h>

#define I_IMG 3
#define S_SEQ 64
#define C_CH  512
#define H_IN  18
#define W_IN  18
#define HW    324
#define OH 19
#define OW 19
#define NPIX 361
#define PPIX 400          // padded 20x20 partial plane
#define FT 16
#define NITER 5
#define CSPLIT 8
#define PLW 24            // fwd LDS plane row stride (uints)
#define PLSZ 580          // fwd LDS plane stride (uints)
#define RPW 24            // tr rp row stride
#define CVS 32            // uint slots per convert block
#define CVP 162           // pixels per convert block

typedef unsigned int uint;
typedef unsigned short ushort;

__device__ inline float blk_reduce(float v, float* tmp) {
  #pragma unroll
  for (int o = 32; o > 0; o >>= 1) v += __shfl_down(v, o, 64);
  int lane = threadIdx.x & 63;
  int w = threadIdx.x >> 6;
  if (lane == 0) tmp[w] = v;
  __syncthreads();
  float r = 0.f;
  if (threadIdx.x == 0) {
    int nw = (blockDim.x + 63) >> 6;
    for (int k = 0; k < nw; ++k) r += tmp[k];
  }
  return r;
}

__device__ inline uint pack_bf2(float lo, float hi) {  // RNE f32x2 -> packed bf16x2
  uint ul = __float_as_uint(lo);
  uint uh = __float_as_uint(hi);
  ul = (ul + 0x7fffu + ((ul >> 16) & 1u)) >> 16;
  uh = (uh + 0x7fffu + ((uh >> 16) & 1u)) & 0xffff0000u;
  return ul | uh;
}

__device__ inline float4 wg_fuse(float4 a, float4 b, float4 c, float rg, float4 w) {
  float4 v;
  v.x = a.x + b.x + c.x + rg * w.x;
  v.y = a.y + b.y + c.y + rg * w.y;
  v.z = a.z + b.z + c.z + rg * w.z;
  v.w = a.w + b.w + c.w + rg * w.w;
  return v;
}

// ---------------------------------------------------------------------------
// convert: feat f32 [n][c][p] -> featT packed-bf16 [n][p][j] (transposed)
//                             -> featP packed-bf16 [n][j][p] (channel-major)
// uint j in [0,256) packs channels (j, j+256). grid (192, 16).
// ---------------------------------------------------------------------------
__global__ __launch_bounds__(256) void convert_k(
    const float* __restrict__ feat, ushort* __restrict__ featT,
    uint* __restrict__ featP)
{
  __shared__ uint tile[CVP * CVS];   // 20736 B
  int tid = threadIdx.x;
  int n = blockIdx.x;
  int yz = blockIdx.y;
  int k0 = (yz >> 1) * CVS;
  int p0 = (yz & 1) * CVP;
  const float* fbase = feat + (size_t)n * C_CH * HW + p0;

  // stage: idx -> (k = idx/81, q = idx%81); lanes walk q (coalesced float2)
  for (int idx = tid; idx < CVS * 81; idx += 256) {
    int k = idx / 81, q = idx - k * 81;
    int j = k0 + k;
    float2 lo = *(const float2*)(fbase + (size_t)j * HW + 2 * q);
    float2 hi = *(const float2*)(fbase + (size_t)(j + 256) * HW + 2 * q);
    uint pk0 = pack_bf2(lo.x, hi.x);
    uint pk1 = pack_bf2(lo.y, hi.y);
    uint b = (uint)(2 * q) * CVS + (uint)(k ^ (q & 31));  // XOR bank swizzle
    tile[b] = pk0;
    tile[b + CVS] = pk1;
    uint2 pp; pp.x = pk0; pp.y = pk1;
    *(uint2*)(featP + ((size_t)n * 256 + j) * HW + p0 + 2 * q) = pp;
  }
  __syncthreads();

  // output: idx -> (px = idx>>5, k = idx&31); 32 lanes cover one 128B line
  uint* dTb = (uint*)featT + ((size_t)n * HW + p0) * (C_CH / 2) + k0;
  for (int idx = tid; idx < CVP * CVS; idx += 256) {
    int px = idx >> 5, k = idx & 31;
    dTb[(size_t)px * (C_CH / 2) + k] = tile[px * CVS + (k ^ ((px >> 1) & 31))];
  }
}

// ---------------------------------------------------------------------------
// prep: distance map -> label_map, sample_weight, a_lo, a_hi; scalars
// ---------------------------------------------------------------------------
__global__ void prep_k(const float* __restrict__ bb,
                       const float* __restrict__ label_w,
                       const float* __restrict__ mask_w,
                       const float* __restrict__ spatial_w,
                       const float* __restrict__ lsl,
                       const float* __restrict__ freg,
                       float* __restrict__ sw, float* __restrict__ lm,
                       float* __restrict__ alo, float* __restrict__ ahi,
                       float* __restrict__ scal)
{
  int n = blockIdx.x;     // n = i*S + s
  int p = threadIdx.x;
  if (n == 0 && p == 0) {
    scal[0] = expf(lsl[0]);                    // step
    scal[1] = fmaxf(freg[0] * freg[0], 1e-6f); // reg
  }
  if (p >= NPIX) return;
  float bx = bb[n * 4 + 0], by = bb[n * 4 + 1];
  float bw = bb[n * 4 + 2], bh = bb[n * 4 + 3];
  float crow = (by + bh * 0.5f) * (1.f / 16.f);
  float ccol = (bx + bw * 0.5f) * (1.f / 16.f);
  int y = p / OW, x = p - (p / OW) * OW;
  float d0 = (float)y - crow, d1 = (float)x - ccol;
  float dist = sqrtf(d0 * d0 + d1 * d1);
  float bins[5];
  #pragma unroll
  for (int b = 0; b < 4; ++b) bins[b] = fmaxf(1.f - fabsf(dist - (float)b), 0.f);
  bins[4] = fminf(fmaxf(dist - 3.f, 0.f), 1.f);
  float lmv = 0.f, mm = 0.f, sp = 0.f;
  #pragma unroll
  for (int b = 0; b < 5; ++b) {
    lmv += bins[b] * label_w[b];
    mm  += bins[b] * mask_w[b];
    sp  += bins[b] * spatial_w[b];
  }
  float tm = 1.f / (1.f + expf(-mm));
  int idx = n * NPIX + p;
  lm[idx]  = lmv;
  sw[idx]  = 0.57735026918962584f * sp;   // sqrt(1/3) * spatial_weight
  alo[idx] = 0.5f * (1.f - tm);
  ahi[idx] = 0.5f * (1.f + tm);
}

// ---------------------------------------------------------------------------
// forward grouped conv on PACKED bf16 featP: 16 channels per 18.5KB LDS group,
// 4 groups (half the barriers/LDS-reads of fp32 version). Weights fp32.
// Both packed channels accumulate into the same acc.
// blockIdx.y = kc: uint slots kc*32..kc*32+31 (channels j and j+256).
// ---------------------------------------------------------------------------
template<int FUSE>
__global__ __launch_bounds__(192) void conv_fwd_part_k(
    const uint* __restrict__ featP, const float* __restrict__ wcur,
    const float* __restrict__ wgp, const float* __restrict__ scal,
    float* __restrict__ part)
{
  __shared__ __align__(16) uint sfeat[8 * PLSZ];
  int tid = threadIdx.x;
  int n = blockIdx.x;
  int s = n & 63;
  int kc = blockIdx.y;
  const uint* fbase = featP + ((size_t)n * 256 + kc * 32) * HW;
  size_t wrow = (size_t)s * C_CH * FT;
  const size_t istr = (size_t)S_SEQ * C_CH * FT;
  float regv = FUSE ? scal[1] : 0.f;

  for (int idx = tid; idx < 8 * PLSZ; idx += 192) sfeat[idx] = 0u;

  int ch_l = tid / 24;
  int row_l = tid - ch_l * 24;
  bool stager = row_l < 18;

  int pos = tid >> 3;
  int slot = tid & 7;
  bool act = pos < 20;
  int cpos = act ? pos : 19;
  int ty = cpos / 5, tx = cpos - (cpos / 5) * 5;

  float acc[5][4];
  #pragma unroll
  for (int r = 0; r < 5; ++r)
    #pragma unroll
    for (int c = 0; c < 4; ++c) acc[r][c] = 0.f;

  const uint* plane0 = &sfeat[slot * PLSZ + (5 * ty) * PLW + 4 * tx];
  __syncthreads();

  for (int g = 0; g < 4; ++g) {
    if (stager) {
      const uint* src = fbase + (size_t)(g * 8 + ch_l) * HW + row_l * 18;
      uint* dst = &sfeat[ch_l * PLSZ + (row_l + 2) * PLW + 2];
      #pragma unroll
      for (int k = 0; k < 9; ++k) {
        uint2 v = *(const uint2*)(src + 2 * k);
        *(uint2*)(dst + 2 * k) = v;
      }
    }
    __syncthreads();

    int j = kc * 32 + g * 8 + slot;          // lo channel j, hi channel j+256
    size_t olo = wrow + (size_t)j * FT;
    size_t ohi = wrow + (size_t)(j + 256) * FT;
    const float4* wpl = (const float4*)(wcur + olo);
    const float4* wph = (const float4*)(wcur + ohi);
    float4 wl0 = wpl[0], wl1 = wpl[1], wl2 = wpl[2], wl3 = wpl[3];
    float4 wh0 = wph[0], wh1 = wph[1], wh2 = wph[2], wh3 = wph[3];
    if (FUSE) {
      const float4* a0 = (const float4*)(wgp + olo);
      const float4* a1 = (const float4*)(wgp + istr + olo);
      const float4* a2 = (const float4*)(wgp + 2 * istr + olo);
      wl0 = wg_fuse(a0[0], a1[0], a2[0], regv, wl0);
      wl1 = wg_fuse(a0[1], a1[1], a2[1], regv, wl1);
      wl2 = wg_fuse(a0[2], a1[2], a2[2], regv, wl2);
      wl3 = wg_fuse(a0[3], a1[3], a2[3], regv, wl3);
      const float4* b0 = (const float4*)(wgp + ohi);
      const float4* b1 = (const float4*)(wgp + istr + ohi);
      const float4* b2 = (const float4*)(wgp + 2 * istr + ohi);
      wh0 = wg_fuse(b0[0], b1[0], b2[0], regv, wh0);
      wh1 = wg_fuse(b0[1], b1[1], b2[1], regv, wh1);
      wh2 = wg_fuse(b0[2], b1[2], b2[2], regv, wh2);
      wh3 = wg_fuse(b0[3], b1[3], b2[3], regv, wh3);
    }

    #pragma unroll
    for (int ri = 0; ri < 8; ++ri) {
      uint4 A = *(const uint4*)(plane0 + ri * PLW);
      uint4 B = *(const uint4*)(plane0 + ri * PLW + 4);
      float fl[7], fh[7];
      fl[0] = __uint_as_float(A.x << 16); fh[0] = __uint_as_float(A.x & 0xffff0000u);
      fl[1] = __uint_as_float(A.y << 16); fh[1] = __uint_as_float(A.y & 0xffff0000u);
      fl[2] = __uint_as_float(A.z << 16); fh[2] = __uint_as_float(A.z & 0xffff0000u);
      fl[3] = __uint_as_float(A.w << 16); fh[3] = __uint_as_float(A.w & 0xffff0000u);
      fl[4] = __uint_as_float(B.x << 16); fh[4] = __uint_as_float(B.x & 0xffff0000u);
      fl[5] = __uint_as_float(B.y << 16); fh[5] = __uint_as_float(B.y & 0xffff0000u);
      fl[6] = __uint_as_float(B.z << 16); fh[6] = __uint_as_float(B.z & 0xffff0000u);
      #pragma unroll
      for (int dy = 0; dy < 4; ++dy) {
        int r = ri - dy;
        if (r < 0 || r > 4) continue;
        float4 wl = (dy == 0) ? wl0 : (dy == 1) ? wl1 : (dy == 2) ? wl2 : wl3;
        float4 wh = (dy == 0) ? wh0 : (dy == 1) ? wh1 : (dy == 2) ? wh2 : wh3;
        #pragma unroll
        for (int c = 0; c < 4; ++c) {
          float a = acc[r][c];
          a = fmaf(fl[c + 0], wl.x, a); a = fmaf(fl[c + 1], wl.y, a);
          a = fmaf(fl[c + 2], wl.z, a); a = fmaf(fl[c + 3], wl.w, a);
          a = fmaf(fh[c + 0], wh.x, a); a = fmaf(fh[c + 1], wh.y, a);
          a = fmaf(fh[c + 2], wh.z, a); a = fmaf(fh[c + 3], wh.w, a);
          acc[r][c] = a;
        }
      }
    }
    __syncthreads();
  }

  #pragma unroll
  for (int r = 0; r < 5; ++r)
    #pragma unroll
    for (int c = 0; c < 4; ++c) {
      float v = acc[r][c];
      v += __shfl_xor(v, 1, 64);
      v += __shfl_xor(v, 2, 64);
      v += __shfl_xor(v, 4, 64);
      acc[r][c] = v;
    }

  int orow = 5 * ty + slot;
  if (act && slot < 5 && orow < OH) {
    float4 v = make_float4(acc[slot][0], acc[slot][1], acc[slot][2], acc[slot][3]);
    *(float4*)(part + ((size_t)n * CSPLIT + kc) * PPIX + orow * 20 + 4 * tx) = v;
  }
}

// ---------------------------------------------------------------------------
// combine0 (once): sum partials -> scores buffer + mask + residuals
// ---------------------------------------------------------------------------
__global__ __launch_bounds__(384) void combine0_k(
    const float* __restrict__ part,
    const float* __restrict__ sw, const float* __restrict__ lm,
    const float* __restrict__ alo, const float* __restrict__ ahi,
    float* __restrict__ scores,
    float* __restrict__ mask, float* __restrict__ rbuf)
{
  int n = blockIdx.x;
  int p = threadIdx.x;
  if (p >= NPIX) return;
  int y = p / OW, x = p - y * OW;
  const float* pb = part + (size_t)n * CSPLIT * PPIX + y * 20 + x;
  float sv = 0.f;
  #pragma unroll
  for (int k = 0; k < CSPLIT; ++k) sv += pb[k * PPIX];
  int idx = n * NPIX + p;
  scores[idx] = sv;
  float lo = alo[idx], hi = ahi[idx], s_w = sw[idx], l_v = lm[idx];
  float sgn = (sv > 0.f) ? 1.f : ((sv < 0.f) ? -1.f : 0.f);
  float actv = lo * fabsf(sv) + hi * sv;
  float msk = lo * sgn + hi;
  mask[idx] = msk;
  rbuf[idx] = msk * s_w * s_w * (actv - l_v);
}

// ---------------------------------------------------------------------------
// transpose conv v2 on packed featT: uint j packs channels (j, j+256).
// ---------------------------------------------------------------------------
__global__ __launch_bounds__(256) void conv_tr2_k(
    const ushort* __restrict__ featT, const float* __restrict__ r,
    float* __restrict__ wgp)
{
  __shared__ __align__(16) float rp[21 * RPW];
  int tid = threadIdx.x;
  int i = blockIdx.x >> 1;
  int cq = blockIdx.x & 1;
  int s = blockIdx.y;
  int cp = tid >> 1, h = tid & 1;
  int j = cq * 128 + cp;     // uint slot; channels (j, j+256)

  for (int idx = tid; idx < 21 * RPW; idx += 256) rp[idx] = 0.f;
  __syncthreads();
  for (int idx = tid; idx < NPIX; idx += 256) {
    int y = idx / OW, x = idx - y * OW;
    rp[(y + 1) * RPW + (x + 1)] = r[(size_t)(i * S_SEQ + s) * NPIX + idx];
  }
  __syncthreads();

  float acc0[FT], acc1[FT];
  #pragma unroll
  for (int t = 0; t < FT; ++t) { acc0[t] = 0.f; acc1[t] = 0.f; }

  const uint* fbu = (const uint*)featT + (size_t)(i * S_SEQ + s) * HW * (C_CH / 2)
                    + j;

  for (int uu = 0; uu < 9; ++uu) {
    int u = h * 9 + uu;
    float rw[4][24];
    #pragma unroll
    for (int dy = 0; dy < 4; ++dy) {
      const float4* rr = (const float4*)&rp[(u + 3 - dy) * RPW];
      #pragma unroll
      for (int q = 0; q < 6; ++q) {
        float4 v = rr[q];
        rw[dy][4 * q + 0] = v.x; rw[dy][4 * q + 1] = v.y;
        rw[dy][4 * q + 2] = v.z; rw[dy][4 * q + 3] = v.w;
      }
    }
    uint fv[18];
    #pragma unroll
    for (int v = 0; v < 18; ++v)
      fv[v] = fbu[(size_t)(u * 18 + v) * (C_CH / 2)];
    #pragma unroll
    for (int v = 0; v < 18; ++v) {
      float f0 = __uint_as_float(fv[v] << 16);
      float f1 = __uint_as_float(fv[v] & 0xffff0000u);
      #pragma unroll
      for (int dy = 0; dy < 4; ++dy) {
        #pragma unroll
        for (int dx = 0; dx < 4; ++dx) {
          acc0[dy * 4 + dx] = fmaf(f0, rw[dy][v + 3 - dx], acc0[dy * 4 + dx]);
          acc1[dy * 4 + dx] = fmaf(f1, rw[dy][v + 3 - dx], acc1[dy * 4 + dx]);
        }
      }
    }
  }

  #pragma unroll
  for (int t = 0; t < FT; ++t) {
    acc0[t] += __shfl_xor(acc0[t], 1, 64);
    acc1[t] += __shfl_xor(acc1[t], 1, 64);
  }

  float out[FT];
  #pragma unroll
  for (int t = 0; t < FT; ++t) out[t] = h ? acc1[t] : acc0[t];
  int c = j + h * 256;
  float4* dst = (float4*)(wgp + (((size_t)i * S_SEQ + s) * C_CH + c) * FT);
  dst[0] = make_float4(out[0], out[1], out[2], out[3]);
  dst[1] = make_float4(out[4], out[5], out[6], out[7]);
  dst[2] = make_float4(out[8], out[9], out[10], out[11]);
  dst[3] = make_float4(out[12], out[13], out[14], out[15]);
}

// ---------------------------------------------------------------------------
// update (1024 threads): den from sg partials, num = ||wg||^2, alpha,
// weight step, incremental scores update, next mask/residuals.
// ---------------------------------------------------------------------------
__global__ __launch_bounds__(1024) void update_k(
    float* __restrict__ wcur, const float* __restrict__ wgp,
    const float* __restrict__ partb,
    const float* __restrict__ sw, const float* __restrict__ lm,
    const float* __restrict__ alo, const float* __restrict__ ahi,
    float* __restrict__ scores, float* __restrict__ mask,
    float* __restrict__ rbuf, const float* __restrict__ scal)
{
  __shared__ float rtmp1[16];
  __shared__ float rtmp2[16];
  __shared__ float s_sa;
  int s = blockIdx.x;
  int tid = threadIdx.x;
  float regv = scal[1];

  float sgl[2];
  float sq = 0.f;
  #pragma unroll
  for (int k = 0; k < 2; ++k) {
    int g = tid + k * 1024;
    sgl[k] = 0.f;
    if (g < I_IMG * NPIX) {
      int i = g / NPIX, p = g - i * NPIX;
      int n = i * S_SEQ + s;
      int y = p / OW, x = p - y * OW;
      const float* pb = partb + (size_t)n * CSPLIT * PPIX + y * 20 + x;
      float sv = 0.f;
      #pragma unroll
      for (int kk = 0; kk < CSPLIT; ++kk) sv += pb[kk * PPIX];
      sgl[k] = sv;
      int idx = n * NPIX + p;
      float sg = sw[idx] * mask[idx] * sv;
      sq += sg * sg;
    }
  }
  float den = blk_reduce(sq, rtmp1);

  size_t base = (size_t)s * C_CH * FT;
  size_t istr = (size_t)S_SEQ * C_CH * FT;
  const float4* p0 = (const float4*)(wgp + base);
  const float4* p1 = (const float4*)(wgp + istr + base);
  const float4* p2 = (const float4*)(wgp + 2 * istr + base);
  float4* pw = (float4*)(wcur + base);
  float sq2 = 0.f;
  for (int g = tid; g < C_CH * FT / 4; g += 1024) {
    float4 v = wg_fuse(p0[g], p1[g], p2[g], regv, pw[g]);
    sq2 += v.x * v.x + v.y * v.y + v.z * v.z + v.w * v.w;
  }
  float num = blk_reduce(sq2, rtmp2);

  if (tid == 0) {
    float step = scal[0];
    float d = fmaxf(den + regv * num, 1e-8f);
    s_sa = step * (num / d);
  }
  __syncthreads();
  float sa = s_sa;

  for (int g = tid; g < C_CH * FT / 4; g += 1024) {
    float4 w = pw[g];
    float4 v = wg_fuse(p0[g], p1[g], p2[g], regv, w);
    w.x -= sa * v.x; w.y -= sa * v.y; w.z -= sa * v.z; w.w -= sa * v.w;
    pw[g] = w;
  }

  #pragma unroll
  for (int k = 0; k < 2; ++k) {
    int g = tid + k * 1024;
    if (g < I_IMG * NPIX) {
      int i = g / NPIX, p = g - i * NPIX;
      int idx = (i * S_SEQ + s) * NPIX + p;
      float sv = scores[idx] - sa * sgl[k];
      scores[idx] = sv;
      float lo = alo[idx], hi = ahi[idx], s_w = sw[idx], l_v = lm[idx];
      float sgn = (sv > 0.f) ? 1.f : ((sv < 0.f) ? -1.f : 0.f);
      float actv = lo * fabsf(sv) + hi * sv;
      float msk = lo * sgn + hi;
      mask[idx] = msk;
      rbuf[idx] = msk * s_w * s_w * (actv - l_v);
    }
  }
}

// ---------------------------------------------------------------------------
extern "C" void kernel_launch(void* const* d_in, const int* in_sizes, int n_in,
                              void* d_out, int out_size, void* d_ws, size_t ws_size,
                              hipStream_t stream)
{
  const float* w_in = (const float*)d_in[0];
  const float* feat = (const float*)d_in[1];
  const float* bb   = (const float*)d_in[2];
  const float* lblw = (const float*)d_in[3];
  const float* mskw = (const float*)d_in[4];
  const float* spw  = (const float*)d_in[5];
  const float* lsl  = (const float*)d_in[6];
  const float* freg = (const float*)d_in[7];

  float* base = (float*)d_ws;
  const int NMAP = I_IMG * S_SEQ * NPIX;   // 69312
  const int NW   = S_SEQ * C_CH * FT;      // 524288
  float* sw     = base;
  float* lm     = sw + NMAP;
  float* alo    = lm + NMAP;
  float* ahi    = alo + NMAP;
  float* mask   = ahi + NMAP;
  float* rbuf   = mask + NMAP;
  float* scores = rbuf + NMAP;
  float* wcur   = scores + NMAP;
  float* wgp    = wcur + NW;               // 3*NW
  float* scal   = wgp + 3 * NW;
  float* partb  = scal + 8;                // I*S*CSPLIT*PPIX = 614400
  ushort* featT = (ushort*)(partb + (size_t)I_IMG * S_SEQ * CSPLIT * PPIX);
  uint* featP   = (uint*)(featT + (size_t)I_IMG * S_SEQ * HW * C_CH);

  convert_k<<<dim3(I_IMG * S_SEQ, 16), 256, 0, stream>>>(feat, featT, featP);
  prep_k<<<I_IMG * S_SEQ, 384, 0, stream>>>(bb, lblw, mskw, spw, lsl, freg,
                                            sw, lm, alo, ahi, scal);
  hipMemcpyAsync(wcur, w_in, (size_t)NW * sizeof(float),
                 hipMemcpyDeviceToDevice, stream);

  // initial scores (only forward conv of wcur)
  conv_fwd_part_k<0><<<dim3(I_IMG * S_SEQ, CSPLIT), 192, 0, stream>>>(
      featP, wcur, nullptr, scal, partb);
  combine0_k<<<I_IMG * S_SEQ, 384, 0, stream>>>(
      partb, sw, lm, alo, ahi, scores, mask, rbuf);

  for (int it = 0; it < NITER; ++it) {
    conv_tr2_k<<<dim3(6, S_SEQ), 256, 0, stream>>>(featT, rbuf, wgp);
    conv_fwd_part_k<1><<<dim3(I_IMG * S_SEQ, CSPLIT), 192, 0, stream>>>(
        featP, wcur, wgp, scal, partb);
    update_k<<<S_SEQ, 1024, 0, stream>>>(
        wcur, wgp, partb, sw, lm, alo, ahi, scores, mask, rbuf, scal);
  }
  hipMemcpyAsync(d_out, wcur, (size_t)NW * sizeof(float),
                 hipMemcpyDeviceToDevice, stream);
}

// Round 13
// 566.562 us; speedup vs baseline: 1.0069x; 1.0069x over previous
//
#include <hip/hip_runtime.h>
#include <math.h>

#define I_IMG 3
#define S_SEQ 64
#define C_CH  512
#define H_IN  18
#define W_IN  18
#define HW    324
#define OH 19
#define OW 19
#define NPIX 361
#define PPIX 400          // padded 20x20 partial plane
#define FT 16
#define NITER 5
#define CSPLIT 8
#define CPB 64            // channels per conv_fwd block
#define PLW 24            // fwd LDS plane row stride (floats)
#define PLSZ 580          // fwd LDS plane stride
#define RPW 24            // tr rp row stride
#define CVS 32            // uint slots per convert block
#define CVP 162           // pixels per convert block

typedef unsigned int uint;
typedef unsigned short ushort;

__device__ inline float blk_reduce(float v, float* tmp) {
  #pragma unroll
  for (int o = 32; o > 0; o >>= 1) v += __shfl_down(v, o, 64);
  int lane = threadIdx.x & 63;
  int w = threadIdx.x >> 6;
  if (lane == 0) tmp[w] = v;
  __syncthreads();
  float r = 0.f;
  if (threadIdx.x == 0) {
    int nw = (blockDim.x + 63) >> 6;
    for (int k = 0; k < nw; ++k) r += tmp[k];
  }
  return r;
}

__device__ inline uint pack_bf2(float lo, float hi) {  // RNE f32x2 -> packed bf16x2
  uint ul = __float_as_uint(lo);
  uint uh = __float_as_uint(hi);
  ul = (ul + 0x7fffu + ((ul >> 16) & 1u)) >> 16;
  uh = (uh + 0x7fffu + ((uh >> 16) & 1u)) & 0xffff0000u;
  return ul | uh;
}

// ---------------------------------------------------------------------------
// convert (R11-proven): feat f32 [n][c][p] -> featT packed-bf16 [n][p][j],
// uint j in [0,256) packs channels (j, j+256). grid (192, 16).
// ---------------------------------------------------------------------------
__global__ __launch_bounds__(256) void convert_k(
    const float* __restrict__ feat, ushort* __restrict__ featT)
{
  __shared__ uint tile[CVP * CVS];   // 20736 B
  int tid = threadIdx.x;
  int n = blockIdx.x;
  int yz = blockIdx.y;
  int k0 = (yz >> 1) * CVS;
  int p0 = (yz & 1) * CVP;
  const float* fbase = feat + (size_t)n * C_CH * HW + p0;

  for (int idx = tid; idx < CVS * 81; idx += 256) {
    int k = idx / 81, q = idx - k * 81;
    int j = k0 + k;
    float2 lo = *(const float2*)(fbase + (size_t)j * HW + 2 * q);
    float2 hi = *(const float2*)(fbase + (size_t)(j + 256) * HW + 2 * q);
    uint b = (uint)(2 * q) * CVS + (uint)(k ^ (q & 31));  // XOR bank swizzle
    tile[b] = pack_bf2(lo.x, hi.x);
    tile[b + CVS] = pack_bf2(lo.y, hi.y);
  }
  __syncthreads();

  uint* dTb = (uint*)featT + ((size_t)n * HW + p0) * (C_CH / 2) + k0;
  for (int idx = tid; idx < CVP * CVS; idx += 256) {
    int px = idx >> 5, k = idx & 31;
    dTb[(size_t)px * (C_CH / 2) + k] = tile[px * CVS + (k ^ ((px >> 1) & 31))];
  }
}

// ---------------------------------------------------------------------------
// prep: distance map -> label_map, sample_weight, a_lo, a_hi; scalars
// ---------------------------------------------------------------------------
__global__ void prep_k(const float* __restrict__ bb,
                       const float* __restrict__ label_w,
                       const float* __restrict__ mask_w,
                       const float* __restrict__ spatial_w,
                       const float* __restrict__ lsl,
                       const float* __restrict__ freg,
                       float* __restrict__ sw, float* __restrict__ lm,
                       float* __restrict__ alo, float* __restrict__ ahi,
                       float* __restrict__ scal)
{
  int n = blockIdx.x;     // n = i*S + s
  int p = threadIdx.x;
  if (n == 0 && p == 0) {
    scal[0] = expf(lsl[0]);                    // step
    scal[1] = fmaxf(freg[0] * freg[0], 1e-6f); // reg
  }
  if (p >= NPIX) return;
  float bx = bb[n * 4 + 0], by = bb[n * 4 + 1];
  float bw = bb[n * 4 + 2], bh = bb[n * 4 + 3];
  float crow = (by + bh * 0.5f) * (1.f / 16.f);
  float ccol = (bx + bw * 0.5f) * (1.f / 16.f);
  int y = p / OW, x = p - (p / OW) * OW;
  float d0 = (float)y - crow, d1 = (float)x - ccol;
  float dist = sqrtf(d0 * d0 + d1 * d1);
  float bins[5];
  #pragma unroll
  for (int b = 0; b < 4; ++b) bins[b] = fmaxf(1.f - fabsf(dist - (float)b), 0.f);
  bins[4] = fminf(fmaxf(dist - 3.f, 0.f), 1.f);
  float lmv = 0.f, mm = 0.f, sp = 0.f;
  #pragma unroll
  for (int b = 0; b < 5; ++b) {
    lmv += bins[b] * label_w[b];
    mm  += bins[b] * mask_w[b];
    sp  += bins[b] * spatial_w[b];
  }
  float tm = 1.f / (1.f + expf(-mm));
  int idx = n * NPIX + p;
  lm[idx]  = lmv;
  sw[idx]  = 0.57735026918962584f * sp;   // sqrt(1/3) * spatial_weight
  alo[idx] = 0.5f * (1.f - tm);
  ahi[idx] = 0.5f * (1.f + tm);
}

// ---------------------------------------------------------------------------
// forward grouped conv on fp32 feat, single-buffer + T14 async-stage split:
// issue group g+1 global loads into regs BEFORE compute(g); ds_write after
// the post-compute barrier. Global latency hides under compute.
// ---------------------------------------------------------------------------
__global__ __launch_bounds__(192) void conv_fwd_part_k(
    const float* __restrict__ feat, const float* __restrict__ wsrc,
    float* __restrict__ part)
{
  __shared__ __align__(16) float sfeat[8 * PLSZ];
  int tid = threadIdx.x;
  int n = blockIdx.x;
  int s = n & 63;
  int kc = blockIdx.y;
  const float* fbase = feat + ((size_t)n * C_CH + kc * CPB) * HW;
  const float* wbase = wsrc + ((size_t)s * C_CH + kc * CPB) * FT;

  for (int idx = tid; idx < 8 * PLSZ; idx += 192) sfeat[idx] = 0.f;

  int ch_l = tid / 24;
  int row_l = tid - ch_l * 24;
  bool stager = row_l < 18;
  const float* srow0 = fbase + (size_t)ch_l * HW + row_l * 18;
  float* dstl = &sfeat[ch_l * PLSZ + (row_l + 2) * PLW + 2];

  int pos = tid >> 3;
  int slot = tid & 7;
  bool act = pos < 20;
  int cpos = act ? pos : 19;
  int ty = cpos / 5, tx = cpos - (cpos / 5) * 5;

  float acc[5][4];
  #pragma unroll
  for (int r = 0; r < 5; ++r)
    #pragma unroll
    for (int c = 0; c < 4; ++c) acc[r][c] = 0.f;

  const float* plane0 = &sfeat[slot * PLSZ + (5 * ty) * PLW + 4 * tx];
  __syncthreads();   // zeros visible

  // prologue: stage group 0 directly
  if (stager) {
    #pragma unroll
    for (int k = 0; k < 9; ++k) {
      float2 v = *(const float2*)(srow0 + 2 * k);
      *(float2*)(dstl + 2 * k) = v;
    }
  }
  __syncthreads();

  for (int c0 = 0; c0 < CPB; c0 += 8) {
    // T14 phase 1: issue next group's loads into regs (no wait)
    float2 pre[9];
    bool havenext = (c0 + 8) < CPB;
    if (havenext && stager) {
      const float* src = srow0 + (size_t)(c0 + 8) * HW;
      #pragma unroll
      for (int k = 0; k < 9; ++k) pre[k] = *(const float2*)(src + 2 * k);
    }

    const float4* wp = (const float4*)(wbase + (size_t)(c0 + slot) * FT);
    float4 w0 = wp[0], w1 = wp[1], w2 = wp[2], w3 = wp[3];

    // compute current group from LDS (global loads draining meanwhile)
    #pragma unroll
    for (int ri = 0; ri < 8; ++ri) {
      float4 ra = *(const float4*)(plane0 + ri * PLW);
      float4 rb = *(const float4*)(plane0 + ri * PLW + 4);
      #pragma unroll
      for (int dy = 0; dy < 4; ++dy) {
        int r = ri - dy;
        if (r < 0 || r > 4) continue;
        float4 wr = (dy == 0) ? w0 : (dy == 1) ? w1 : (dy == 2) ? w2 : w3;
        acc[r][0] = fmaf(ra.x, wr.x, acc[r][0]); acc[r][0] = fmaf(ra.y, wr.y, acc[r][0]);
        acc[r][0] = fmaf(ra.z, wr.z, acc[r][0]); acc[r][0] = fmaf(ra.w, wr.w, acc[r][0]);
        acc[r][1] = fmaf(ra.y, wr.x, acc[r][1]); acc[r][1] = fmaf(ra.z, wr.y, acc[r][1]);
        acc[r][1] = fmaf(ra.w, wr.z, acc[r][1]); acc[r][1] = fmaf(rb.x, wr.w, acc[r][1]);
        acc[r][2] = fmaf(ra.z, wr.x, acc[r][2]); acc[r][2] = fmaf(ra.w, wr.y, acc[r][2]);
        acc[r][2] = fmaf(rb.x, wr.z, acc[r][2]); acc[r][2] = fmaf(rb.y, wr.w, acc[r][2]);
        acc[r][3] = fmaf(ra.w, wr.x, acc[r][3]); acc[r][3] = fmaf(rb.x, wr.y, acc[r][3]);
        acc[r][3] = fmaf(rb.y, wr.z, acc[r][3]); acc[r][3] = fmaf(rb.z, wr.w, acc[r][3]);
      }
    }
    __syncthreads();   // all reads of current group done

    // T14 phase 2: write prefetched group into LDS
    if (havenext && stager) {
      #pragma unroll
      for (int k = 0; k < 9; ++k) *(float2*)(dstl + 2 * k) = pre[k];
    }
    __syncthreads();   // writes visible for next iteration
  }

  #pragma unroll
  for (int r = 0; r < 5; ++r)
    #pragma unroll
    for (int c = 0; c < 4; ++c) {
      float v = acc[r][c];
      v += __shfl_xor(v, 1, 64);
      v += __shfl_xor(v, 2, 64);
      v += __shfl_xor(v, 4, 64);
      acc[r][c] = v;
    }

  int orow = 5 * ty + slot;
  if (act && slot < 5 && orow < OH) {
    float4 v = make_float4(acc[slot][0], acc[slot][1], acc[slot][2], acc[slot][3]);
    *(float4*)(part + ((size_t)n * CSPLIT + kc) * PPIX + orow * 20 + 4 * tx) = v;
  }
}

// ---------------------------------------------------------------------------
// combine0 (once): sum partials -> scores buffer + mask + residuals
// ---------------------------------------------------------------------------
__global__ __launch_bounds__(384) void combine0_k(
    const float* __restrict__ part,
    const float* __restrict__ sw, const float* __restrict__ lm,
    const float* __restrict__ alo, const float* __restrict__ ahi,
    float* __restrict__ scores,
    float* __restrict__ mask, float* __restrict__ rbuf)
{
  int n = blockIdx.x;
  int p = threadIdx.x;
  if (p >= NPIX) return;
  int y = p / OW, x = p - y * OW;
  const float* pb = part + (size_t)n * CSPLIT * PPIX + y * 20 + x;
  float sv = 0.f;
  #pragma unroll
  for (int k = 0; k < CSPLIT; ++k) sv += pb[k * PPIX];
  int idx = n * NPIX + p;
  scores[idx] = sv;
  float lo = alo[idx], hi = ahi[idx], s_w = sw[idx], l_v = lm[idx];
  float sgn = (sv > 0.f) ? 1.f : ((sv < 0.f) ? -1.f : 0.f);
  float actv = lo * fabsf(sv) + hi * sv;
  float msk = lo * sgn + hi;
  mask[idx] = msk;
  rbuf[idx] = msk * s_w * s_w * (actv - l_v);
}

// ---------------------------------------------------------------------------
// transpose conv v2 on packed featT: uint j packs channels (j, j+256).
// ---------------------------------------------------------------------------
__global__ __launch_bounds__(256) void conv_tr2_k(
    const ushort* __restrict__ featT, const float* __restrict__ r,
    float* __restrict__ wgp)
{
  __shared__ __align__(16) float rp[21 * RPW];
  int tid = threadIdx.x;
  int i = blockIdx.x >> 1;
  int cq = blockIdx.x & 1;
  int s = blockIdx.y;
  int cp = tid >> 1, h = tid & 1;
  int j = cq * 128 + cp;     // uint slot; channels (j, j+256)

  for (int idx = tid; idx < 21 * RPW; idx += 256) rp[idx] = 0.f;
  __syncthreads();
  for (int idx = tid; idx < NPIX; idx += 256) {
    int y = idx / OW, x = idx - y * OW;
    rp[(y + 1) * RPW + (x + 1)] = r[(size_t)(i * S_SEQ + s) * NPIX + idx];
  }
  __syncthreads();

  float acc0[FT], acc1[FT];
  #pragma unroll
  for (int t = 0; t < FT; ++t) { acc0[t] = 0.f; acc1[t] = 0.f; }

  const uint* fbu = (const uint*)featT + (size_t)(i * S_SEQ + s) * HW * (C_CH / 2)
                    + j;

  for (int uu = 0; uu < 9; ++uu) {
    int u = h * 9 + uu;
    float rw[4][24];
    #pragma unroll
    for (int dy = 0; dy < 4; ++dy) {
      const float4* rr = (const float4*)&rp[(u + 3 - dy) * RPW];
      #pragma unroll
      for (int q = 0; q < 6; ++q) {
        float4 v = rr[q];
        rw[dy][4 * q + 0] = v.x; rw[dy][4 * q + 1] = v.y;
        rw[dy][4 * q + 2] = v.z; rw[dy][4 * q + 3] = v.w;
      }
    }
    uint fv[18];
    #pragma unroll
    for (int v = 0; v < 18; ++v)
      fv[v] = fbu[(size_t)(u * 18 + v) * (C_CH / 2)];
    #pragma unroll
    for (int v = 0; v < 18; ++v) {
      float f0 = __uint_as_float(fv[v] << 16);
      float f1 = __uint_as_float(fv[v] & 0xffff0000u);
      #pragma unroll
      for (int dy = 0; dy < 4; ++dy) {
        #pragma unroll
        for (int dx = 0; dx < 4; ++dx) {
          acc0[dy * 4 + dx] = fmaf(f0, rw[dy][v + 3 - dx], acc0[dy * 4 + dx]);
          acc1[dy * 4 + dx] = fmaf(f1, rw[dy][v + 3 - dx], acc1[dy * 4 + dx]);
        }
      }
    }
  }

  #pragma unroll
  for (int t = 0; t < FT; ++t) {
    acc0[t] += __shfl_xor(acc0[t], 1, 64);
    acc1[t] += __shfl_xor(acc1[t], 1, 64);
  }

  float out[FT];
  #pragma unroll
  for (int t = 0; t < FT; ++t) out[t] = h ? acc1[t] : acc0[t];
  int c = j + h * 256;
  float4* dst = (float4*)(wgp + (((size_t)i * S_SEQ + s) * C_CH + c) * FT);
  dst[0] = make_float4(out[0], out[1], out[2], out[3]);
  dst[1] = make_float4(out[4], out[5], out[6], out[7]);
  dst[2] = make_float4(out[8], out[9], out[10], out[11]);
  dst[3] = make_float4(out[12], out[13], out[14], out[15]);
}

// ---------------------------------------------------------------------------
// combine_wg: wg = sum_i wgp + reg*wcur; nump[s] = ||wg||^2
// ---------------------------------------------------------------------------
__global__ __launch_bounds__(256) void combine_wg_k(
    const float* __restrict__ wgp, const float* __restrict__ wcur,
    const float* __restrict__ scal,
    float* __restrict__ wg, float* __restrict__ nump)
{
  __shared__ float rtmp[4];
  int s = blockIdx.x;
  int tid = threadIdx.x;
  float regv = scal[1];
  size_t base = (size_t)s * C_CH * FT;
  size_t istr = (size_t)S_SEQ * C_CH * FT;
  const float4* p0 = (const float4*)(wgp + base);
  const float4* p1 = (const float4*)(wgp + istr + base);
  const float4* p2 = (const float4*)(wgp + 2 * istr + base);
  const float4* pw = (const float4*)(wcur + base);
  float4* pg = (float4*)(wg + base);
  float sq = 0.f;
  for (int g = tid; g < C_CH * FT / 4; g += 256) {
    float4 a = p0[g], b = p1[g], c = p2[g], w = pw[g];
    float4 v;
    v.x = a.x + b.x + c.x + regv * w.x;
    v.y = a.y + b.y + c.y + regv * w.y;
    v.z = a.z + b.z + c.z + regv * w.z;
    v.w = a.w + b.w + c.w + regv * w.w;
    pg[g] = v;
    sq += v.x * v.x + v.y * v.y + v.z * v.z + v.w * v.w;
  }
  float tot = blk_reduce(sq, rtmp);
  if (tid == 0) nump[s] = tot;
}

// ---------------------------------------------------------------------------
// update: den from sg partials, alpha, weight step, incremental scores update,
// next-iteration mask/residuals.
// ---------------------------------------------------------------------------
__global__ __launch_bounds__(256) void update_k(
    float* __restrict__ wcur, const float* __restrict__ wg,
    const float* __restrict__ partb,
    const float* __restrict__ sw, const float* __restrict__ lm,
    const float* __restrict__ alo, const float* __restrict__ ahi,
    float* __restrict__ scores, float* __restrict__ mask,
    float* __restrict__ rbuf,
    const float* __restrict__ nump, const float* __restrict__ scal)
{
  __shared__ float rtmp[4];
  __shared__ float s_sa;
  int s = blockIdx.x;
  int tid = threadIdx.x;

  float sgl[5];
  float sq = 0.f;
  #pragma unroll
  for (int k = 0; k < 5; ++k) {
    int g = tid + k * 256;
    sgl[k] = 0.f;
    if (g < I_IMG * NPIX) {
      int i = g / NPIX, p = g - i * NPIX;
      int n = i * S_SEQ + s;
      int y = p / OW, x = p - y * OW;
      const float* pb = partb + (size_t)n * CSPLIT * PPIX + y * 20 + x;
      float sv = 0.f;
      #pragma unroll
      for (int kk = 0; kk < CSPLIT; ++kk) sv += pb[kk * PPIX];
      sgl[k] = sv;
      int idx = n * NPIX + p;
      float sg = sw[idx] * mask[idx] * sv;
      sq += sg * sg;
    }
  }
  float den = blk_reduce(sq, rtmp);
  if (tid == 0) {
    float num = nump[s];
    float regv = scal[1], step = scal[0];
    float d = fmaxf(den + regv * num, 1e-8f);
    s_sa = step * (num / d);
  }
  __syncthreads();
  float sa = s_sa;

  float4* w4 = (float4*)(wcur + (size_t)s * (C_CH * FT));
  const float4* g4 = (const float4*)(wg + (size_t)s * (C_CH * FT));
  for (int idx = tid; idx < C_CH * FT / 4; idx += 256) {
    float4 w = w4[idx], g = g4[idx];
    w.x -= sa * g.x; w.y -= sa * g.y; w.z -= sa * g.z; w.w -= sa * g.w;
    w4[idx] = w;
  }

  #pragma unroll
  for (int k = 0; k < 5; ++k) {
    int g = tid + k * 256;
    if (g < I_IMG * NPIX) {
      int i = g / NPIX, p = g - i * NPIX;
      int idx = (i * S_SEQ + s) * NPIX + p;
      float sv = scores[idx] - sa * sgl[k];
      scores[idx] = sv;
      float lo = alo[idx], hi = ahi[idx], s_w = sw[idx], l_v = lm[idx];
      float sgn = (sv > 0.f) ? 1.f : ((sv < 0.f) ? -1.f : 0.f);
      float actv = lo * fabsf(sv) + hi * sv;
      float msk = lo * sgn + hi;
      mask[idx] = msk;
      rbuf[idx] = msk * s_w * s_w * (actv - l_v);
    }
  }
}

// ---------------------------------------------------------------------------
extern "C" void kernel_launch(void* const* d_in, const int* in_sizes, int n_in,
                              void* d_out, int out_size, void* d_ws, size_t ws_size,
                              hipStream_t stream)
{
  const float* w_in = (const float*)d_in[0];
  const float* feat = (const float*)d_in[1];
  const float* bb   = (const float*)d_in[2];
  const float* lblw = (const float*)d_in[3];
  const float* mskw = (const float*)d_in[4];
  const float* spw  = (const float*)d_in[5];
  const float* lsl  = (const float*)d_in[6];
  const float* freg = (const float*)d_in[7];

  float* base = (float*)d_ws;
  const int NMAP = I_IMG * S_SEQ * NPIX;   // 69312
  const int NW   = S_SEQ * C_CH * FT;      // 524288
  float* sw     = base;
  float* lm     = sw + NMAP;
  float* alo    = lm + NMAP;
  float* ahi    = alo + NMAP;
  float* mask   = ahi + NMAP;
  float* rbuf   = mask + NMAP;
  float* scores = rbuf + NMAP;
  float* wcur   = scores + NMAP;
  float* wg     = wcur + NW;
  float* wgp    = wg + NW;                 // 3*NW
  float* nump   = wgp + 3 * NW;
  float* scal   = nump + S_SEQ;
  float* partb  = scal + 8;                // I*S*CSPLIT*PPIX = 614400
  ushort* featT = (ushort*)(partb + (size_t)I_IMG * S_SEQ * CSPLIT * PPIX);

  convert_k<<<dim3(I_IMG * S_SEQ, 16), 256, 0, stream>>>(feat, featT);
  prep_k<<<I_IMG * S_SEQ, 384, 0, stream>>>(bb, lblw, mskw, spw, lsl, freg,
                                            sw, lm, alo, ahi, scal);
  hipMemcpyAsync(wcur, w_in, (size_t)NW * sizeof(float),
                 hipMemcpyDeviceToDevice, stream);

  // initial scores (only forward conv of wcur)
  conv_fwd_part_k<<<dim3(I_IMG * S_SEQ, CSPLIT), 192, 0, stream>>>(
      feat, wcur, partb);
  combine0_k<<<I_IMG * S_SEQ, 384, 0, stream>>>(
      partb, sw, lm, alo, ahi, scores, mask, rbuf);

  for (int it = 0; it < NITER; ++it) {
    conv_tr2_k<<<dim3(6, S_SEQ), 256, 0, stream>>>(featT, rbuf, wgp);
    combine_wg_k<<<S_SEQ, 256, 0, stream>>>(wgp, wcur, scal, wg, nump);
    conv_fwd_part_k<<<dim3(I_IMG * S_SEQ, CSPLIT), 192, 0, stream>>>(
        feat, wg, partb);
    update_k<<<S_SEQ, 256, 0, stream>>>(
        wcur, wg, partb, sw, lm, alo, ahi, scores, mask, rbuf, nump, scal);
  }
  hipMemcpyAsync(d_out, wcur, (size_t)NW * sizeof(float),
                 hipMemcpyDeviceToDevice, stream);
}

// Round 14
// 544.845 us; speedup vs baseline: 1.0470x; 1.0399x over previous
//
#include <hip/hip_runtime.h>
#include <math.h>

#define I_IMG 3
#define S_SEQ 64
#define C_CH  512
#define H_IN  18
#define W_IN  18
#define HW    324
#define OH 19
#define OW 19
#define NPIX 361
#define PPIX 400          // padded 20x20 partial plane
#define FT 16
#define NITER 5
#define CSPLIT 8
#define CPB 64            // channels per conv_fwd block
#define PLW 24            // fwd LDS plane row stride (floats)
#define PLSZ 580          // fwd LDS plane stride
#define RPW 24            // tr rp row stride
#define CVS 32            // uint slots per convert block
#define CVP 162           // pixels per convert block

typedef unsigned int uint;
typedef unsigned short ushort;

__device__ inline float blk_reduce(float v, float* tmp) {
  #pragma unroll
  for (int o = 32; o > 0; o >>= 1) v += __shfl_down(v, o, 64);
  int lane = threadIdx.x & 63;
  int w = threadIdx.x >> 6;
  if (lane == 0) tmp[w] = v;
  __syncthreads();
  float r = 0.f;
  if (threadIdx.x == 0) {
    int nw = (blockDim.x + 63) >> 6;
    for (int k = 0; k < nw; ++k) r += tmp[k];
  }
  return r;
}

__device__ inline uint pack_bf2(float lo, float hi) {  // RNE f32x2 -> packed bf16x2
  uint ul = __float_as_uint(lo);
  uint uh = __float_as_uint(hi);
  ul = (ul + 0x7fffu + ((ul >> 16) & 1u)) >> 16;
  uh = (uh + 0x7fffu + ((uh >> 16) & 1u)) & 0xffff0000u;
  return ul | uh;
}

__device__ inline uint pack_bf2_adj(float a, float b) { // (a,b) -> bf16(a)|bf16(b)<<16
  uint ua = __float_as_uint(a);
  uint ub = __float_as_uint(b);
  ua = (ua + 0x7fffu + ((ua >> 16) & 1u)) >> 16;
  ub = (ub + 0x7fffu + ((ub >> 16) & 1u)) & 0xffff0000u;
  return ua | ub;
}

// ---------------------------------------------------------------------------
// convert: feat f32 [n][c][p] ->
//   featT packed-bf16 [n][p][j] (j packs channels (j, j+256))  [for conv_tr]
//   featB bf16 [n][c][p] (straight layout)                     [for conv_fwd]
// grid (192, 16): block = (n, 32 slots x 162 px). R11-proven transpose path.
// ---------------------------------------------------------------------------
__global__ __launch_bounds__(256) void convert_k(
    const float* __restrict__ feat, ushort* __restrict__ featT,
    ushort* __restrict__ featB)
{
  __shared__ uint tile[CVP * CVS];   // 20736 B
  int tid = threadIdx.x;
  int n = blockIdx.x;
  int yz = blockIdx.y;
  int k0 = (yz >> 1) * CVS;
  int p0 = (yz & 1) * CVP;
  const float* fbase = feat + (size_t)n * C_CH * HW + p0;
  uint* dBb = (uint*)(featB + (size_t)n * C_CH * HW + p0);  // p0,HW even -> ok

  for (int idx = tid; idx < CVS * 81; idx += 256) {
    int k = idx / 81, q = idx - k * 81;
    int j = k0 + k;
    float2 lo = *(const float2*)(fbase + (size_t)j * HW + 2 * q);
    float2 hi = *(const float2*)(fbase + (size_t)(j + 256) * HW + 2 * q);
    uint b = (uint)(2 * q) * CVS + (uint)(k ^ (q & 31));  // XOR bank swizzle
    tile[b] = pack_bf2(lo.x, hi.x);
    tile[b + CVS] = pack_bf2(lo.y, hi.y);
    // straight bf16 copies (coalesced within each channel row)
    dBb[((size_t)j * HW + 2 * q) >> 1] = pack_bf2_adj(lo.x, lo.y);
    dBb[((size_t)(j + 256) * HW + 2 * q) >> 1] = pack_bf2_adj(hi.x, hi.y);
  }
  __syncthreads();

  uint* dTb = (uint*)featT + ((size_t)n * HW + p0) * (C_CH / 2) + k0;
  for (int idx = tid; idx < CVP * CVS; idx += 256) {
    int px = idx >> 5, k = idx & 31;
    dTb[(size_t)px * (C_CH / 2) + k] = tile[px * CVS + (k ^ ((px >> 1) & 31))];
  }
}

// ---------------------------------------------------------------------------
// prep: distance map -> label_map, sample_weight, a_lo, a_hi; scalars
// ---------------------------------------------------------------------------
__global__ void prep_k(const float* __restrict__ bb,
                       const float* __restrict__ label_w,
                       const float* __restrict__ mask_w,
                       const float* __restrict__ spatial_w,
                       const float* __restrict__ lsl,
                       const float* __restrict__ freg,
                       float* __restrict__ sw, float* __restrict__ lm,
                       float* __restrict__ alo, float* __restrict__ ahi,
                       float* __restrict__ scal)
{
  int n = blockIdx.x;     // n = i*S + s
  int p = threadIdx.x;
  if (n == 0 && p == 0) {
    scal[0] = expf(lsl[0]);                    // step
    scal[1] = fmaxf(freg[0] * freg[0], 1e-6f); // reg
  }
  if (p >= NPIX) return;
  float bx = bb[n * 4 + 0], by = bb[n * 4 + 1];
  float bw = bb[n * 4 + 2], bh = bb[n * 4 + 3];
  float crow = (by + bh * 0.5f) * (1.f / 16.f);
  float ccol = (bx + bw * 0.5f) * (1.f / 16.f);
  int y = p / OW, x = p - (p / OW) * OW;
  float d0 = (float)y - crow, d1 = (float)x - ccol;
  float dist = sqrtf(d0 * d0 + d1 * d1);
  float bins[5];
  #pragma unroll
  for (int b = 0; b < 4; ++b) bins[b] = fmaxf(1.f - fabsf(dist - (float)b), 0.f);
  bins[4] = fminf(fmaxf(dist - 3.f, 0.f), 1.f);
  float lmv = 0.f, mm = 0.f, sp = 0.f;
  #pragma unroll
  for (int b = 0; b < 5; ++b) {
    lmv += bins[b] * label_w[b];
    mm  += bins[b] * mask_w[b];
    sp  += bins[b] * spatial_w[b];
  }
  float tm = 1.f / (1.f + expf(-mm));
  int idx = n * NPIX + p;
  lm[idx]  = lmv;
  sw[idx]  = 0.57735026918962584f * sp;   // sqrt(1/3) * spatial_weight
  alo[idx] = 0.5f * (1.f - tm);
  ahi[idx] = 0.5f * (1.f + tm);
}

// ---------------------------------------------------------------------------
// forward grouped conv: R9-proven structure; staging reads bf16 featB
// (half the bytes + half the load instrs) and converts to fp32 at LDS write.
// Inner compute loop identical fp32 (no unpack in hot loop).
// ---------------------------------------------------------------------------
__global__ __launch_bounds__(192) void conv_fwd_part_k(
    const ushort* __restrict__ featB, const float* __restrict__ wsrc,
    float* __restrict__ part)
{
  __shared__ __align__(16) float sfeat[8 * PLSZ];
  int tid = threadIdx.x;
  int n = blockIdx.x;
  int s = n & 63;
  int kc = blockIdx.y;
  const ushort* fbase = featB + ((size_t)n * C_CH + kc * CPB) * HW;
  const float* wbase = wsrc + ((size_t)s * C_CH + kc * CPB) * FT;

  for (int idx = tid; idx < 8 * PLSZ; idx += 192) sfeat[idx] = 0.f;

  int ch_l = tid / 24;
  int row_l = tid - ch_l * 24;
  bool stager = row_l < 18;

  int pos = tid >> 3;
  int slot = tid & 7;
  bool act = pos < 20;
  int cpos = act ? pos : 19;
  int ty = cpos / 5, tx = cpos - (cpos / 5) * 5;

  float acc[5][4];
  #pragma unroll
  for (int r = 0; r < 5; ++r)
    #pragma unroll
    for (int c = 0; c < 4; ++c) acc[r][c] = 0.f;

  const float* plane0 = &sfeat[slot * PLSZ + (5 * ty) * PLW + 4 * tx];
  __syncthreads();

  for (int c0 = 0; c0 < CPB; c0 += 8) {
    if (stager) {
      const uint* src = (const uint*)(fbase + (size_t)(c0 + ch_l) * HW + row_l * 18);
      float* dst = &sfeat[ch_l * PLSZ + (row_l + 2) * PLW + 2];
      #pragma unroll
      for (int k = 0; k < 9; ++k) {
        uint v = src[k];
        float2 w;
        w.x = __uint_as_float(v << 16);
        w.y = __uint_as_float(v & 0xffff0000u);
        *(float2*)(dst + 2 * k) = w;
      }
    }
    __syncthreads();

    const float4* wp = (const float4*)(wbase + (size_t)(c0 + slot) * FT);
    float4 w0 = wp[0], w1 = wp[1], w2 = wp[2], w3 = wp[3];

    #pragma unroll
    for (int ri = 0; ri < 8; ++ri) {
      float4 ra = *(const float4*)(plane0 + ri * PLW);
      float4 rb = *(const float4*)(plane0 + ri * PLW + 4);
      #pragma unroll
      for (int dy = 0; dy < 4; ++dy) {
        int r = ri - dy;
        if (r < 0 || r > 4) continue;
        float4 wr = (dy == 0) ? w0 : (dy == 1) ? w1 : (dy == 2) ? w2 : w3;
        acc[r][0] = fmaf(ra.x, wr.x, acc[r][0]); acc[r][0] = fmaf(ra.y, wr.y, acc[r][0]);
        acc[r][0] = fmaf(ra.z, wr.z, acc[r][0]); acc[r][0] = fmaf(ra.w, wr.w, acc[r][0]);
        acc[r][1] = fmaf(ra.y, wr.x, acc[r][1]); acc[r][1] = fmaf(ra.z, wr.y, acc[r][1]);
        acc[r][1] = fmaf(ra.w, wr.z, acc[r][1]); acc[r][1] = fmaf(rb.x, wr.w, acc[r][1]);
        acc[r][2] = fmaf(ra.z, wr.x, acc[r][2]); acc[r][2] = fmaf(ra.w, wr.y, acc[r][2]);
        acc[r][2] = fmaf(rb.x, wr.z, acc[r][2]); acc[r][2] = fmaf(rb.y, wr.w, acc[r][2]);
        acc[r][3] = fmaf(ra.w, wr.x, acc[r][3]); acc[r][3] = fmaf(rb.x, wr.y, acc[r][3]);
        acc[r][3] = fmaf(rb.y, wr.z, acc[r][3]); acc[r][3] = fmaf(rb.z, wr.w, acc[r][3]);
      }
    }
    __syncthreads();
  }

  #pragma unroll
  for (int r = 0; r < 5; ++r)
    #pragma unroll
    for (int c = 0; c < 4; ++c) {
      float v = acc[r][c];
      v += __shfl_xor(v, 1, 64);
      v += __shfl_xor(v, 2, 64);
      v += __shfl_xor(v, 4, 64);
      acc[r][c] = v;
    }

  int orow = 5 * ty + slot;
  if (act && slot < 5 && orow < OH) {
    float4 v = make_float4(acc[slot][0], acc[slot][1], acc[slot][2], acc[slot][3]);
    *(float4*)(part + ((size_t)n * CSPLIT + kc) * PPIX + orow * 20 + 4 * tx) = v;
  }
}

// ---------------------------------------------------------------------------
// combine0 (once): sum partials -> scores buffer + mask + residuals
// ---------------------------------------------------------------------------
__global__ __launch_bounds__(384) void combine0_k(
    const float* __restrict__ part,
    const float* __restrict__ sw, const float* __restrict__ lm,
    const float* __restrict__ alo, const float* __restrict__ ahi,
    float* __restrict__ scores,
    float* __restrict__ mask, float* __restrict__ rbuf)
{
  int n = blockIdx.x;
  int p = threadIdx.x;
  if (p >= NPIX) return;
  int y = p / OW, x = p - y * OW;
  const float* pb = part + (size_t)n * CSPLIT * PPIX + y * 20 + x;
  float sv = 0.f;
  #pragma unroll
  for (int k = 0; k < CSPLIT; ++k) sv += pb[k * PPIX];
  int idx = n * NPIX + p;
  scores[idx] = sv;
  float lo = alo[idx], hi = ahi[idx], s_w = sw[idx], l_v = lm[idx];
  float sgn = (sv > 0.f) ? 1.f : ((sv < 0.f) ? -1.f : 0.f);
  float actv = lo * fabsf(sv) + hi * sv;
  float msk = lo * sgn + hi;
  mask[idx] = msk;
  rbuf[idx] = msk * s_w * s_w * (actv - l_v);
}

// ---------------------------------------------------------------------------
// transpose conv v2 on packed featT: uint j packs channels (j, j+256).
// ---------------------------------------------------------------------------
__global__ __launch_bounds__(256) void conv_tr2_k(
    const ushort* __restrict__ featT, const float* __restrict__ r,
    float* __restrict__ wgp)
{
  __shared__ __align__(16) float rp[21 * RPW];
  int tid = threadIdx.x;
  int i = blockIdx.x >> 1;
  int cq = blockIdx.x & 1;
  int s = blockIdx.y;
  int cp = tid >> 1, h = tid & 1;
  int j = cq * 128 + cp;     // uint slot; channels (j, j+256)

  for (int idx = tid; idx < 21 * RPW; idx += 256) rp[idx] = 0.f;
  __syncthreads();
  for (int idx = tid; idx < NPIX; idx += 256) {
    int y = idx / OW, x = idx - y * OW;
    rp[(y + 1) * RPW + (x + 1)] = r[(size_t)(i * S_SEQ + s) * NPIX + idx];
  }
  __syncthreads();

  float acc0[FT], acc1[FT];
  #pragma unroll
  for (int t = 0; t < FT; ++t) { acc0[t] = 0.f; acc1[t] = 0.f; }

  const uint* fbu = (const uint*)featT + (size_t)(i * S_SEQ + s) * HW * (C_CH / 2)
                    + j;

  for (int uu = 0; uu < 9; ++uu) {
    int u = h * 9 + uu;
    float rw[4][24];
    #pragma unroll
    for (int dy = 0; dy < 4; ++dy) {
      const float4* rr = (const float4*)&rp[(u + 3 - dy) * RPW];
      #pragma unroll
      for (int q = 0; q < 6; ++q) {
        float4 v = rr[q];
        rw[dy][4 * q + 0] = v.x; rw[dy][4 * q + 1] = v.y;
        rw[dy][4 * q + 2] = v.z; rw[dy][4 * q + 3] = v.w;
      }
    }
    uint fv[18];
    #pragma unroll
    for (int v = 0; v < 18; ++v)
      fv[v] = fbu[(size_t)(u * 18 + v) * (C_CH / 2)];
    #pragma unroll
    for (int v = 0; v < 18; ++v) {
      float f0 = __uint_as_float(fv[v] << 16);
      float f1 = __uint_as_float(fv[v] & 0xffff0000u);
      #pragma unroll
      for (int dy = 0; dy < 4; ++dy) {
        #pragma unroll
        for (int dx = 0; dx < 4; ++dx) {
          acc0[dy * 4 + dx] = fmaf(f0, rw[dy][v + 3 - dx], acc0[dy * 4 + dx]);
          acc1[dy * 4 + dx] = fmaf(f1, rw[dy][v + 3 - dx], acc1[dy * 4 + dx]);
        }
      }
    }
  }

  #pragma unroll
  for (int t = 0; t < FT; ++t) {
    acc0[t] += __shfl_xor(acc0[t], 1, 64);
    acc1[t] += __shfl_xor(acc1[t], 1, 64);
  }

  float out[FT];
  #pragma unroll
  for (int t = 0; t < FT; ++t) out[t] = h ? acc1[t] : acc0[t];
  int c = j + h * 256;
  float4* dst = (float4*)(wgp + (((size_t)i * S_SEQ + s) * C_CH + c) * FT);
  dst[0] = make_float4(out[0], out[1], out[2], out[3]);
  dst[1] = make_float4(out[4], out[5], out[6], out[7]);
  dst[2] = make_float4(out[8], out[9], out[10], out[11]);
  dst[3] = make_float4(out[12], out[13], out[14], out[15]);
}

// ---------------------------------------------------------------------------
// combine_wg: wg = sum_i wgp + reg*wcur; nump[s] = ||wg||^2
// ---------------------------------------------------------------------------
__global__ __launch_bounds__(256) void combine_wg_k(
    const float* __restrict__ wgp, const float* __restrict__ wcur,
    const float* __restrict__ scal,
    float* __restrict__ wg, float* __restrict__ nump)
{
  __shared__ float rtmp[4];
  int s = blockIdx.x;
  int tid = threadIdx.x;
  float regv = scal[1];
  size_t base = (size_t)s * C_CH * FT;
  size_t istr = (size_t)S_SEQ * C_CH * FT;
  const float4* p0 = (const float4*)(wgp + base);
  const float4* p1 = (const float4*)(wgp + istr + base);
  const float4* p2 = (const float4*)(wgp + 2 * istr + base);
  const float4* pw = (const float4*)(wcur + base);
  float4* pg = (float4*)(wg + base);
  float sq = 0.f;
  for (int g = tid; g < C_CH * FT / 4; g += 256) {
    float4 a = p0[g], b = p1[g], c = p2[g], w = pw[g];
    float4 v;
    v.x = a.x + b.x + c.x + regv * w.x;
    v.y = a.y + b.y + c.y + regv * w.y;
    v.z = a.z + b.z + c.z + regv * w.z;
    v.w = a.w + b.w + c.w + regv * w.w;
    pg[g] = v;
    sq += v.x * v.x + v.y * v.y + v.z * v.z + v.w * v.w;
  }
  float tot = blk_reduce(sq, rtmp);
  if (tid == 0) nump[s] = tot;
}

// ---------------------------------------------------------------------------
// update: den from sg partials, alpha, weight step, incremental scores update,
// next-iteration mask/residuals.
// ---------------------------------------------------------------------------
__global__ __launch_bounds__(256) void update_k(
    float* __restrict__ wcur, const float* __restrict__ wg,
    const float* __restrict__ partb,
    const float* __restrict__ sw, const float* __restrict__ lm,
    const float* __restrict__ alo, const float* __restrict__ ahi,
    float* __restrict__ scores, float* __restrict__ mask,
    float* __restrict__ rbuf,
    const float* __restrict__ nump, const float* __restrict__ scal)
{
  __shared__ float rtmp[4];
  __shared__ float s_sa;
  int s = blockIdx.x;
  int tid = threadIdx.x;

  float sgl[5];
  float sq = 0.f;
  #pragma unroll
  for (int k = 0; k < 5; ++k) {
    int g = tid + k * 256;
    sgl[k] = 0.f;
    if (g < I_IMG * NPIX) {
      int i = g / NPIX, p = g - i * NPIX;
      int n = i * S_SEQ + s;
      int y = p / OW, x = p - y * OW;
      const float* pb = partb + (size_t)n * CSPLIT * PPIX + y * 20 + x;
      float sv = 0.f;
      #pragma unroll
      for (int kk = 0; kk < CSPLIT; ++kk) sv += pb[kk * PPIX];
      sgl[k] = sv;
      int idx = n * NPIX + p;
      float sg = sw[idx] * mask[idx] * sv;
      sq += sg * sg;
    }
  }
  float den = blk_reduce(sq, rtmp);
  if (tid == 0) {
    float num = nump[s];
    float regv = scal[1], step = scal[0];
    float d = fmaxf(den + regv * num, 1e-8f);
    s_sa = step * (num / d);
  }
  __syncthreads();
  float sa = s_sa;

  float4* w4 = (float4*)(wcur + (size_t)s * (C_CH * FT));
  const float4* g4 = (const float4*)(wg + (size_t)s * (C_CH * FT));
  for (int idx = tid; idx < C_CH * FT / 4; idx += 256) {
    float4 w = w4[idx], g = g4[idx];
    w.x -= sa * g.x; w.y -= sa * g.y; w.z -= sa * g.z; w.w -= sa * g.w;
    w4[idx] = w;
  }

  #pragma unroll
  for (int k = 0; k < 5; ++k) {
    int g = tid + k * 256;
    if (g < I_IMG * NPIX) {
      int i = g / NPIX, p = g - i * NPIX;
      int idx = (i * S_SEQ + s) * NPIX + p;
      float sv = scores[idx] - sa * sgl[k];
      scores[idx] = sv;
      float lo = alo[idx], hi = ahi[idx], s_w = sw[idx], l_v = lm[idx];
      float sgn = (sv > 0.f) ? 1.f : ((sv < 0.f) ? -1.f : 0.f);
      float actv = lo * fabsf(sv) + hi * sv;
      float msk = lo * sgn + hi;
      mask[idx] = msk;
      rbuf[idx] = msk * s_w * s_w * (actv - l_v);
    }
  }
}

// ---------------------------------------------------------------------------
extern "C" void kernel_launch(void* const* d_in, const int* in_sizes, int n_in,
                              void* d_out, int out_size, void* d_ws, size_t ws_size,
                              hipStream_t stream)
{
  const float* w_in = (const float*)d_in[0];
  const float* feat = (const float*)d_in[1];
  const float* bb   = (const float*)d_in[2];
  const float* lblw = (const float*)d_in[3];
  const float* mskw = (const float*)d_in[4];
  const float* spw  = (const float*)d_in[5];
  const float* lsl  = (const float*)d_in[6];
  const float* freg = (const float*)d_in[7];

  float* base = (float*)d_ws;
  const int NMAP = I_IMG * S_SEQ * NPIX;   // 69312
  const int NW   = S_SEQ * C_CH * FT;      // 524288
  float* sw     = base;
  float* lm     = sw + NMAP;
  float* alo    = lm + NMAP;
  float* ahi    = alo + NMAP;
  float* mask   = ahi + NMAP;
  float* rbuf   = mask + NMAP;
  float* scores = rbuf + NMAP;
  float* wcur   = scores + NMAP;
  float* wg     = wcur + NW;
  float* wgp    = wg + NW;                 // 3*NW
  float* nump   = wgp + 3 * NW;
  float* scal   = nump + S_SEQ;
  float* partb  = scal + 8;                // I*S*CSPLIT*PPIX = 614400
  ushort* featT = (ushort*)(partb + (size_t)I_IMG * S_SEQ * CSPLIT * PPIX);
  ushort* featB = featT + (size_t)I_IMG * S_SEQ * HW * C_CH;

  convert_k<<<dim3(I_IMG * S_SEQ, 16), 256, 0, stream>>>(feat, featT, featB);
  prep_k<<<I_IMG * S_SEQ, 384, 0, stream>>>(bb, lblw, mskw, spw, lsl, freg,
                                            sw, lm, alo, ahi, scal);
  hipMemcpyAsync(wcur, w_in, (size_t)NW * sizeof(float),
                 hipMemcpyDeviceToDevice, stream);

  // initial scores (only forward conv of wcur)
  conv_fwd_part_k<<<dim3(I_IMG * S_SEQ, CSPLIT), 192, 0, stream>>>(
      featB, wcur, partb);
  combine0_k<<<I_IMG * S_SEQ, 384, 0, stream>>>(
      partb, sw, lm, alo, ahi, scores, mask, rbuf);

  for (int it = 0; it < NITER; ++it) {
    conv_tr2_k<<<dim3(6, S_SEQ), 256, 0, stream>>>(featT, rbuf, wgp);
    combine_wg_k<<<S_SEQ, 256, 0, stream>>>(wgp, wcur, scal, wg, nump);
    conv_fwd_part_k<<<dim3(I_IMG * S_SEQ, CSPLIT), 192, 0, stream>>>(
        featB, wg, partb);
    update_k<<<S_SEQ, 256, 0, stream>>>(
        wcur, wg, partb, sw, lm, alo, ahi, scores, mask, rbuf, nump, scal);
  }
  hipMemcpyAsync(d_out, wcur, (size_t)NW * sizeof(float),
                 hipMemcpyDeviceToDevice, stream);
}

// Round 15
// 518.727 us; speedup vs baseline: 1.0998x; 1.0504x over previous
//
#include <hip/hip_runtime.h>
#include <math.h>

#define I_IMG 3
#define S_SEQ 64
#define C_CH  512
#define H_IN  18
#define W_IN  18
#define HW    324
#define OH 19
#define OW 19
#define NPIX 361
#define PPIX 400          // padded 20x20 partial plane
#define FT 16
#define NITER 5
#define CSPLIT 8
#define CPB 64            // channels per conv_fwd block
#define PLW 24            // fwd LDS plane row stride (floats)
#define PLSZ 580          // fwd LDS plane stride
#define RPW 24            // tr rp row stride
#define CVS 32            // uint slots per convert block
#define CVP 162           // pixels per convert block
#define NWGP 6            // wgp partials: 3 images x 2 u-halves

typedef unsigned int uint;
typedef unsigned short ushort;

__device__ inline float blk_reduce(float v, float* tmp) {
  #pragma unroll
  for (int o = 32; o > 0; o >>= 1) v += __shfl_down(v, o, 64);
  int lane = threadIdx.x & 63;
  int w = threadIdx.x >> 6;
  if (lane == 0) tmp[w] = v;
  __syncthreads();
  float r = 0.f;
  if (threadIdx.x == 0) {
    int nw = (blockDim.x + 63) >> 6;
    for (int k = 0; k < nw; ++k) r += tmp[k];
  }
  return r;
}

__device__ inline uint pack_bf2(float lo, float hi) {  // RNE f32x2 -> packed bf16x2
  uint ul = __float_as_uint(lo);
  uint uh = __float_as_uint(hi);
  ul = (ul + 0x7fffu + ((ul >> 16) & 1u)) >> 16;
  uh = (uh + 0x7fffu + ((uh >> 16) & 1u)) & 0xffff0000u;
  return ul | uh;
}

// ---------------------------------------------------------------------------
// convert (R11 exact): feat f32 [n][c][p] -> featT packed-bf16 [n][p][j],
// uint j in [0,256) packs channels (j, j+256). grid (192, 16).
// ---------------------------------------------------------------------------
__global__ __launch_bounds__(256) void convert_k(
    const float* __restrict__ feat, ushort* __restrict__ featT)
{
  __shared__ uint tile[CVP * CVS];   // 20736 B
  int tid = threadIdx.x;
  int n = blockIdx.x;
  int yz = blockIdx.y;
  int k0 = (yz >> 1) * CVS;
  int p0 = (yz & 1) * CVP;
  const float* fbase = feat + (size_t)n * C_CH * HW + p0;

  for (int idx = tid; idx < CVS * 81; idx += 256) {
    int k = idx / 81, q = idx - k * 81;
    int j = k0 + k;
    float2 lo = *(const float2*)(fbase + (size_t)j * HW + 2 * q);
    float2 hi = *(const float2*)(fbase + (size_t)(j + 256) * HW + 2 * q);
    uint b = (uint)(2 * q) * CVS + (uint)(k ^ (q & 31));  // XOR bank swizzle
    tile[b] = pack_bf2(lo.x, hi.x);
    tile[b + CVS] = pack_bf2(lo.y, hi.y);
  }
  __syncthreads();

  uint* dTb = (uint*)featT + ((size_t)n * HW + p0) * (C_CH / 2) + k0;
  for (int idx = tid; idx < CVP * CVS; idx += 256) {
    int px = idx >> 5, k = idx & 31;
    dTb[(size_t)px * (C_CH / 2) + k] = tile[px * CVS + (k ^ ((px >> 1) & 31))];
  }
}

// ---------------------------------------------------------------------------
// prep: distance map -> label_map, sample_weight, a_lo, a_hi; scalars
// ---------------------------------------------------------------------------
__global__ void prep_k(const float* __restrict__ bb,
                       const float* __restrict__ label_w,
                       const float* __restrict__ mask_w,
                       const float* __restrict__ spatial_w,
                       const float* __restrict__ lsl,
                       const float* __restrict__ freg,
                       float* __restrict__ sw, float* __restrict__ lm,
                       float* __restrict__ alo, float* __restrict__ ahi,
                       float* __restrict__ scal)
{
  int n = blockIdx.x;     // n = i*S + s
  int p = threadIdx.x;
  if (n == 0 && p == 0) {
    scal[0] = expf(lsl[0]);                    // step
    scal[1] = fmaxf(freg[0] * freg[0], 1e-6f); // reg
  }
  if (p >= NPIX) return;
  float bx = bb[n * 4 + 0], by = bb[n * 4 + 1];
  float bw = bb[n * 4 + 2], bh = bb[n * 4 + 3];
  float crow = (by + bh * 0.5f) * (1.f / 16.f);
  float ccol = (bx + bw * 0.5f) * (1.f / 16.f);
  int y = p / OW, x = p - (p / OW) * OW;
  float d0 = (float)y - crow, d1 = (float)x - ccol;
  float dist = sqrtf(d0 * d0 + d1 * d1);
  float bins[5];
  #pragma unroll
  for (int b = 0; b < 4; ++b) bins[b] = fmaxf(1.f - fabsf(dist - (float)b), 0.f);
  bins[4] = fminf(fmaxf(dist - 3.f, 0.f), 1.f);
  float lmv = 0.f, mm = 0.f, sp = 0.f;
  #pragma unroll
  for (int b = 0; b < 5; ++b) {
    lmv += bins[b] * label_w[b];
    mm  += bins[b] * mask_w[b];
    sp  += bins[b] * spatial_w[b];
  }
  float tm = 1.f / (1.f + expf(-mm));
  int idx = n * NPIX + p;
  lm[idx]  = lmv;
  sw[idx]  = 0.57735026918962584f * sp;   // sqrt(1/3) * spatial_weight
  alo[idx] = 0.5f * (1.f - tm);
  ahi[idx] = 0.5f * (1.f + tm);
}

// ---------------------------------------------------------------------------
// forward grouped conv on fp32 feat (R9 exact).
// ---------------------------------------------------------------------------
__global__ __launch_bounds__(192) void conv_fwd_part_k(
    const float* __restrict__ feat, const float* __restrict__ wsrc,
    float* __restrict__ part)
{
  __shared__ __align__(16) float sfeat[8 * PLSZ];
  int tid = threadIdx.x;
  int n = blockIdx.x;
  int s = n & 63;
  int kc = blockIdx.y;
  const float* fbase = feat + ((size_t)n * C_CH + kc * CPB) * HW;
  const float* wbase = wsrc + ((size_t)s * C_CH + kc * CPB) * FT;

  for (int idx = tid; idx < 8 * PLSZ; idx += 192) sfeat[idx] = 0.f;

  int ch_l = tid / 24;
  int row_l = tid - ch_l * 24;
  bool stager = row_l < 18;

  int pos = tid >> 3;
  int slot = tid & 7;
  bool act = pos < 20;
  int cpos = act ? pos : 19;
  int ty = cpos / 5, tx = cpos - (cpos / 5) * 5;

  float acc[5][4];
  #pragma unroll
  for (int r = 0; r < 5; ++r)
    #pragma unroll
    for (int c = 0; c < 4; ++c) acc[r][c] = 0.f;

  const float* plane0 = &sfeat[slot * PLSZ + (5 * ty) * PLW + 4 * tx];
  __syncthreads();

  for (int c0 = 0; c0 < CPB; c0 += 8) {
    if (stager) {
      const float* src = fbase + (size_t)(c0 + ch_l) * HW + row_l * 18;
      float* dst = &sfeat[ch_l * PLSZ + (row_l + 2) * PLW + 2];
      #pragma unroll
      for (int k = 0; k < 9; ++k) {
        float2 v = *(const float2*)(src + 2 * k);
        *(float2*)(dst + 2 * k) = v;
      }
    }
    __syncthreads();

    const float4* wp = (const float4*)(wbase + (size_t)(c0 + slot) * FT);
    float4 w0 = wp[0], w1 = wp[1], w2 = wp[2], w3 = wp[3];

    #pragma unroll
    for (int ri = 0; ri < 8; ++ri) {
      float4 ra = *(const float4*)(plane0 + ri * PLW);
      float4 rb = *(const float4*)(plane0 + ri * PLW + 4);
      #pragma unroll
      for (int dy = 0; dy < 4; ++dy) {
        int r = ri - dy;
        if (r < 0 || r > 4) continue;
        float4 wr = (dy == 0) ? w0 : (dy == 1) ? w1 : (dy == 2) ? w2 : w3;
        acc[r][0] = fmaf(ra.x, wr.x, acc[r][0]); acc[r][0] = fmaf(ra.y, wr.y, acc[r][0]);
        acc[r][0] = fmaf(ra.z, wr.z, acc[r][0]); acc[r][0] = fmaf(ra.w, wr.w, acc[r][0]);
        acc[r][1] = fmaf(ra.y, wr.x, acc[r][1]); acc[r][1] = fmaf(ra.z, wr.y, acc[r][1]);
        acc[r][1] = fmaf(ra.w, wr.z, acc[r][1]); acc[r][1] = fmaf(rb.x, wr.w, acc[r][1]);
        acc[r][2] = fmaf(ra.z, wr.x, acc[r][2]); acc[r][2] = fmaf(ra.w, wr.y, acc[r][2]);
        acc[r][2] = fmaf(rb.x, wr.z, acc[r][2]); acc[r][2] = fmaf(rb.y, wr.w, acc[r][2]);
        acc[r][3] = fmaf(ra.w, wr.x, acc[r][3]); acc[r][3] = fmaf(rb.x, wr.y, acc[r][3]);
        acc[r][3] = fmaf(rb.y, wr.z, acc[r][3]); acc[r][3] = fmaf(rb.z, wr.w, acc[r][3]);
      }
    }
    __syncthreads();
  }

  #pragma unroll
  for (int r = 0; r < 5; ++r)
    #pragma unroll
    for (int c = 0; c < 4; ++c) {
      float v = acc[r][c];
      v += __shfl_xor(v, 1, 64);
      v += __shfl_xor(v, 2, 64);
      v += __shfl_xor(v, 4, 64);
      acc[r][c] = v;
    }

  int orow = 5 * ty + slot;
  if (act && slot < 5 && orow < OH) {
    float4 v = make_float4(acc[slot][0], acc[slot][1], acc[slot][2], acc[slot][3]);
    *(float4*)(part + ((size_t)n * CSPLIT + kc) * PPIX + orow * 20 + 4 * tx) = v;
  }
}

// ---------------------------------------------------------------------------
// combine0 (once): sum partials -> scores buffer + mask + residuals
// ---------------------------------------------------------------------------
__global__ __launch_bounds__(384) void combine0_k(
    const float* __restrict__ part,
    const float* __restrict__ sw, const float* __restrict__ lm,
    const float* __restrict__ alo, const float* __restrict__ ahi,
    float* __restrict__ scores,
    float* __restrict__ mask, float* __restrict__ rbuf)
{
  int n = blockIdx.x;
  int p = threadIdx.x;
  if (p >= NPIX) return;
  int y = p / OW, x = p - y * OW;
  const float* pb = part + (size_t)n * CSPLIT * PPIX + y * 20 + x;
  float sv = 0.f;
  #pragma unroll
  for (int k = 0; k < CSPLIT; ++k) sv += pb[k * PPIX];
  int idx = n * NPIX + p;
  scores[idx] = sv;
  float lo = alo[idx], hi = ahi[idx], s_w = sw[idx], l_v = lm[idx];
  float sgn = (sv > 0.f) ? 1.f : ((sv < 0.f) ? -1.f : 0.f);
  float actv = lo * fabsf(sv) + hi * sv;
  float msk = lo * sgn + hi;
  mask[idx] = msk;
  rbuf[idx] = msk * s_w * s_w * (actv - l_v);
}

// ---------------------------------------------------------------------------
// transpose conv v3: u-split for occupancy. grid (12, 64):
// blockIdx.x = i*4 + cq*2 + uh; cq = channel half, uh = uu-range half.
// Each block does uu in [uh?5:0, uh?9:5) -> featT reads partition cleanly.
// Writes partial wgp[(i*2+uh)][s][c][16].
// ---------------------------------------------------------------------------
__global__ __launch_bounds__(256) void conv_tr2_k(
    const ushort* __restrict__ featT, const float* __restrict__ r,
    float* __restrict__ wgp)
{
  __shared__ __align__(16) float rp[21 * RPW];
  int tid = threadIdx.x;
  int bx = blockIdx.x;
  int i = bx >> 2;
  int cq = (bx >> 1) & 1;
  int uh = bx & 1;
  int s = blockIdx.y;
  int cp = tid >> 1, h = tid & 1;
  int j = cq * 128 + cp;     // uint slot; channels (j, j+256)

  for (int idx = tid; idx < 21 * RPW; idx += 256) rp[idx] = 0.f;
  __syncthreads();
  for (int idx = tid; idx < NPIX; idx += 256) {
    int y = idx / OW, x = idx - y * OW;
    rp[(y + 1) * RPW + (x + 1)] = r[(size_t)(i * S_SEQ + s) * NPIX + idx];
  }
  __syncthreads();

  float acc0[FT], acc1[FT];
  #pragma unroll
  for (int t = 0; t < FT; ++t) { acc0[t] = 0.f; acc1[t] = 0.f; }

  const uint* fbu = (const uint*)featT + (size_t)(i * S_SEQ + s) * HW * (C_CH / 2)
                    + j;

  int uu0 = uh ? 5 : 0;
  int uu1 = uh ? 9 : 5;
  for (int uu = uu0; uu < uu1; ++uu) {
    int u = h * 9 + uu;
    float rw[4][24];
    #pragma unroll
    for (int dy = 0; dy < 4; ++dy) {
      const float4* rr = (const float4*)&rp[(u + 3 - dy) * RPW];
      #pragma unroll
      for (int q = 0; q < 6; ++q) {
        float4 v = rr[q];
        rw[dy][4 * q + 0] = v.x; rw[dy][4 * q + 1] = v.y;
        rw[dy][4 * q + 2] = v.z; rw[dy][4 * q + 3] = v.w;
      }
    }
    uint fv[18];
    #pragma unroll
    for (int v = 0; v < 18; ++v)
      fv[v] = fbu[(size_t)(u * 18 + v) * (C_CH / 2)];
    #pragma unroll
    for (int v = 0; v < 18; ++v) {
      float f0 = __uint_as_float(fv[v] << 16);
      float f1 = __uint_as_float(fv[v] & 0xffff0000u);
      #pragma unroll
      for (int dy = 0; dy < 4; ++dy) {
        #pragma unroll
        for (int dx = 0; dx < 4; ++dx) {
          acc0[dy * 4 + dx] = fmaf(f0, rw[dy][v + 3 - dx], acc0[dy * 4 + dx]);
          acc1[dy * 4 + dx] = fmaf(f1, rw[dy][v + 3 - dx], acc1[dy * 4 + dx]);
        }
      }
    }
  }

  #pragma unroll
  for (int t = 0; t < FT; ++t) {
    acc0[t] += __shfl_xor(acc0[t], 1, 64);
    acc1[t] += __shfl_xor(acc1[t], 1, 64);
  }

  float out[FT];
  #pragma unroll
  for (int t = 0; t < FT; ++t) out[t] = h ? acc1[t] : acc0[t];
  int c = j + h * 256;
  float4* dst = (float4*)(wgp +
      (((size_t)(i * 2 + uh) * S_SEQ + s) * C_CH + c) * FT);
  dst[0] = make_float4(out[0], out[1], out[2], out[3]);
  dst[1] = make_float4(out[4], out[5], out[6], out[7]);
  dst[2] = make_float4(out[8], out[9], out[10], out[11]);
  dst[3] = make_float4(out[12], out[13], out[14], out[15]);
}

// ---------------------------------------------------------------------------
// combine_wg: wg = sum of 6 wgp partials + reg*wcur; nump[s] = ||wg||^2
// ---------------------------------------------------------------------------
__global__ __launch_bounds__(256) void combine_wg_k(
    const float* __restrict__ wgp, const float* __restrict__ wcur,
    const float* __restrict__ scal,
    float* __restrict__ wg, float* __restrict__ nump)
{
  __shared__ float rtmp[4];
  int s = blockIdx.x;
  int tid = threadIdx.x;
  float regv = scal[1];
  size_t base = (size_t)s * C_CH * FT;
  size_t istr = (size_t)S_SEQ * C_CH * FT;
  const float4* pp[NWGP];
  #pragma unroll
  for (int k = 0; k < NWGP; ++k)
    pp[k] = (const float4*)(wgp + (size_t)k * istr + base);
  const float4* pw = (const float4*)(wcur + base);
  float4* pg = (float4*)(wg + base);
  float sq = 0.f;
  for (int g = tid; g < C_CH * FT / 4; g += 256) {
    float4 w = pw[g];
    float4 v;
    v.x = regv * w.x; v.y = regv * w.y; v.z = regv * w.z; v.w = regv * w.w;
    #pragma unroll
    for (int k = 0; k < NWGP; ++k) {
      float4 a = pp[k][g];
      v.x += a.x; v.y += a.y; v.z += a.z; v.w += a.w;
    }
    pg[g] = v;
    sq += v.x * v.x + v.y * v.y + v.z * v.z + v.w * v.w;
  }
  float tot = blk_reduce(sq, rtmp);
  if (tid == 0) nump[s] = tot;
}

// ---------------------------------------------------------------------------
// update: den from sg partials, alpha, weight step, incremental scores update,
// next-iteration mask/residuals.
// ---------------------------------------------------------------------------
__global__ __launch_bounds__(256) void update_k(
    float* __restrict__ wcur, const float* __restrict__ wg,
    const float* __restrict__ partb,
    const float* __restrict__ sw, const float* __restrict__ lm,
    const float* __restrict__ alo, const float* __restrict__ ahi,
    float* __restrict__ scores, float* __restrict__ mask,
    float* __restrict__ rbuf,
    const float* __restrict__ nump, const float* __restrict__ scal)
{
  __shared__ float rtmp[4];
  __shared__ float s_sa;
  int s = blockIdx.x;
  int tid = threadIdx.x;

  float sgl[5];
  float sq = 0.f;
  #pragma unroll
  for (int k = 0; k < 5; ++k) {
    int g = tid + k * 256;
    sgl[k] = 0.f;
    if (g < I_IMG * NPIX) {
      int i = g / NPIX, p = g - i * NPIX;
      int n = i * S_SEQ + s;
      int y = p / OW, x = p - y * OW;
      const float* pb = partb + (size_t)n * CSPLIT * PPIX + y * 20 + x;
      float sv = 0.f;
      #pragma unroll
      for (int kk = 0; kk < CSPLIT; ++kk) sv += pb[kk * PPIX];
      sgl[k] = sv;
      int idx = n * NPIX + p;
      float sg = sw[idx] * mask[idx] * sv;
      sq += sg * sg;
    }
  }
  float den = blk_reduce(sq, rtmp);
  if (tid == 0) {
    float num = nump[s];
    float regv = scal[1], step = scal[0];
    float d = fmaxf(den + regv * num, 1e-8f);
    s_sa = step * (num / d);
  }
  __syncthreads();
  float sa = s_sa;

  float4* w4 = (float4*)(wcur + (size_t)s * (C_CH * FT));
  const float4* g4 = (const float4*)(wg + (size_t)s * (C_CH * FT));
  for (int idx = tid; idx < C_CH * FT / 4; idx += 256) {
    float4 w = w4[idx], g = g4[idx];
    w.x -= sa * g.x; w.y -= sa * g.y; w.z -= sa * g.z; w.w -= sa * g.w;
    w4[idx] = w;
  }

  #pragma unroll
  for (int k = 0; k < 5; ++k) {
    int g = tid + k * 256;
    if (g < I_IMG * NPIX) {
      int i = g / NPIX, p = g - i * NPIX;
      int idx = (i * S_SEQ + s) * NPIX + p;
      float sv = scores[idx] - sa * sgl[k];
      scores[idx] = sv;
      float lo = alo[idx], hi = ahi[idx], s_w = sw[idx], l_v = lm[idx];
      float sgn = (sv > 0.f) ? 1.f : ((sv < 0.f) ? -1.f : 0.f);
      float actv = lo * fabsf(sv) + hi * sv;
      float msk = lo * sgn + hi;
      mask[idx] = msk;
      rbuf[idx] = msk * s_w * s_w * (actv - l_v);
    }
  }
}

// ---------------------------------------------------------------------------
extern "C" void kernel_launch(void* const* d_in, const int* in_sizes, int n_in,
                              void* d_out, int out_size, void* d_ws, size_t ws_size,
                              hipStream_t stream)
{
  const float* w_in = (const float*)d_in[0];
  const float* feat = (const float*)d_in[1];
  const float* bb   = (const float*)d_in[2];
  const float* lblw = (const float*)d_in[3];
  const float* mskw = (const float*)d_in[4];
  const float* spw  = (const float*)d_in[5];
  const float* lsl  = (const float*)d_in[6];
  const float* freg = (const float*)d_in[7];

  float* base = (float*)d_ws;
  const int NMAP = I_IMG * S_SEQ * NPIX;   // 69312
  const int NW   = S_SEQ * C_CH * FT;      // 524288
  float* sw     = base;
  float* lm     = sw + NMAP;
  float* alo    = lm + NMAP;
  float* ahi    = alo + NMAP;
  float* mask   = ahi + NMAP;
  float* rbuf   = mask + NMAP;
  float* scores = rbuf + NMAP;
  float* wcur   = scores + NMAP;
  float* wg     = wcur + NW;
  float* wgp    = wg + NW;                 // NWGP*NW
  float* nump   = wgp + (size_t)NWGP * NW;
  float* scal   = nump + S_SEQ;
  float* partb  = scal + 8;                // I*S*CSPLIT*PPIX = 614400
  ushort* featT = (ushort*)(partb + (size_t)I_IMG * S_SEQ * CSPLIT * PPIX);

  convert_k<<<dim3(I_IMG * S_SEQ, 16), 256, 0, stream>>>(feat, featT);
  prep_k<<<I_IMG * S_SEQ, 384, 0, stream>>>(bb, lblw, mskw, spw, lsl, freg,
                                            sw, lm, alo, ahi, scal);
  hipMemcpyAsync(wcur, w_in, (size_t)NW * sizeof(float),
                 hipMemcpyDeviceToDevice, stream);

  // initial scores (only forward conv of wcur)
  conv_fwd_part_k<<<dim3(I_IMG * S_SEQ, CSPLIT), 192, 0, stream>>>(
      feat, wcur, partb);
  combine0_k<<<I_IMG * S_SEQ, 384, 0, stream>>>(
      partb, sw, lm, alo, ahi, scores, mask, rbuf);

  for (int it = 0; it < NITER; ++it) {
    conv_tr2_k<<<dim3(12, S_SEQ), 256, 0, stream>>>(featT, rbuf, wgp);
    combine_wg_k<<<S_SEQ, 256, 0, stream>>>(wgp, wcur, scal, wg, nump);
    conv_fwd_part_k<<<dim3(I_IMG * S_SEQ, CSPLIT), 192, 0, stream>>>(
        feat, wg, partb);
    update_k<<<S_SEQ, 256, 0, stream>>>(
        wcur, wg, partb, sw, lm, alo, ahi, scores, mask, rbuf, nump, scal);
  }
  hipMemcpyAsync(d_out, wcur, (size_t)NW * sizeof(float),
                 hipMemcpyDeviceToDevice, stream);
}

// Round 16
// 508.880 us; speedup vs baseline: 1.1210x; 1.0194x over previous
//
#include <hip/hip_runtime.h>
#include <math.h>

#define I_IMG 3
#define S_SEQ 64
#define C_CH  512
#define H_IN  18
#define W_IN  18
#define HW    324
#define OH 19
#define OW 19
#define NPIX 361
#define PPIX 400          // padded 20x20 partial plane
#define FT 16
#define NITER 5
#define CSPLIT 16         // channel splits for conv_fwd (R16: 8->16)
#define CPB 32            // channels per conv_fwd block
#define PLW 24            // fwd LDS plane row stride (floats)
#define PLSZ 580          // fwd LDS plane stride
#define RPW 24            // tr rp row stride
#define CVS 32            // uint slots per convert block
#define CVP 162           // pixels per convert block

typedef unsigned int uint;
typedef unsigned short ushort;

__device__ inline float blk_reduce(float v, float* tmp) {
  #pragma unroll
  for (int o = 32; o > 0; o >>= 1) v += __shfl_down(v, o, 64);
  int lane = threadIdx.x & 63;
  int w = threadIdx.x >> 6;
  if (lane == 0) tmp[w] = v;
  __syncthreads();
  float r = 0.f;
  if (threadIdx.x == 0) {
    int nw = (blockDim.x + 63) >> 6;
    for (int k = 0; k < nw; ++k) r += tmp[k];
  }
  return r;
}

__device__ inline uint pack_bf2(float lo, float hi) {  // RNE f32x2 -> packed bf16x2
  uint ul = __float_as_uint(lo);
  uint uh = __float_as_uint(hi);
  ul = (ul + 0x7fffu + ((ul >> 16) & 1u)) >> 16;
  uh = (uh + 0x7fffu + ((uh >> 16) & 1u)) & 0xffff0000u;
  return ul | uh;
}

// ---------------------------------------------------------------------------
// convert (R11 exact): feat f32 [n][c][p] -> featT packed-bf16 [n][p][j],
// uint j in [0,256) packs channels (j, j+256). grid (192, 16).
// ---------------------------------------------------------------------------
__global__ __launch_bounds__(256) void convert_k(
    const float* __restrict__ feat, ushort* __restrict__ featT)
{
  __shared__ uint tile[CVP * CVS];   // 20736 B
  int tid = threadIdx.x;
  int n = blockIdx.x;
  int yz = blockIdx.y;
  int k0 = (yz >> 1) * CVS;
  int p0 = (yz & 1) * CVP;
  const float* fbase = feat + (size_t)n * C_CH * HW + p0;

  for (int idx = tid; idx < CVS * 81; idx += 256) {
    int k = idx / 81, q = idx - k * 81;
    int j = k0 + k;
    float2 lo = *(const float2*)(fbase + (size_t)j * HW + 2 * q);
    float2 hi = *(const float2*)(fbase + (size_t)(j + 256) * HW + 2 * q);
    uint b = (uint)(2 * q) * CVS + (uint)(k ^ (q & 31));  // XOR bank swizzle
    tile[b] = pack_bf2(lo.x, hi.x);
    tile[b + CVS] = pack_bf2(lo.y, hi.y);
  }
  __syncthreads();

  uint* dTb = (uint*)featT + ((size_t)n * HW + p0) * (C_CH / 2) + k0;
  for (int idx = tid; idx < CVP * CVS; idx += 256) {
    int px = idx >> 5, k = idx & 31;
    dTb[(size_t)px * (C_CH / 2) + k] = tile[px * CVS + (k ^ ((px >> 1) & 31))];
  }
}

// ---------------------------------------------------------------------------
// prep: distance map -> label_map, sample_weight, a_lo, a_hi; scalars
// ---------------------------------------------------------------------------
__global__ void prep_k(const float* __restrict__ bb,
                       const float* __restrict__ label_w,
                       const float* __restrict__ mask_w,
                       const float* __restrict__ spatial_w,
                       const float* __restrict__ lsl,
                       const float* __restrict__ freg,
                       float* __restrict__ sw, float* __restrict__ lm,
                       float* __restrict__ alo, float* __restrict__ ahi,
                       float* __restrict__ scal)
{
  int n = blockIdx.x;     // n = i*S + s
  int p = threadIdx.x;
  if (n == 0 && p == 0) {
    scal[0] = expf(lsl[0]);                    // step
    scal[1] = fmaxf(freg[0] * freg[0], 1e-6f); // reg
  }
  if (p >= NPIX) return;
  float bx = bb[n * 4 + 0], by = bb[n * 4 + 1];
  float bw = bb[n * 4 + 2], bh = bb[n * 4 + 3];
  float crow = (by + bh * 0.5f) * (1.f / 16.f);
  float ccol = (bx + bw * 0.5f) * (1.f / 16.f);
  int y = p / OW, x = p - (p / OW) * OW;
  float d0 = (float)y - crow, d1 = (float)x - ccol;
  float dist = sqrtf(d0 * d0 + d1 * d1);
  float bins[5];
  #pragma unroll
  for (int b = 0; b < 4; ++b) bins[b] = fmaxf(1.f - fabsf(dist - (float)b), 0.f);
  bins[4] = fminf(fmaxf(dist - 3.f, 0.f), 1.f);
  float lmv = 0.f, mm = 0.f, sp = 0.f;
  #pragma unroll
  for (int b = 0; b < 5; ++b) {
    lmv += bins[b] * label_w[b];
    mm  += bins[b] * mask_w[b];
    sp  += bins[b] * spatial_w[b];
  }
  float tm = 1.f / (1.f + expf(-mm));
  int idx = n * NPIX + p;
  lm[idx]  = lmv;
  sw[idx]  = 0.57735026918962584f * sp;   // sqrt(1/3) * spatial_weight
  alo[idx] = 0.5f * (1.f - tm);
  ahi[idx] = 0.5f * (1.f + tm);
}

// ---------------------------------------------------------------------------
// forward grouped conv on fp32 feat; R9 structure with CPB=32 (CSPLIT=16):
// 3072 blocks -> 8 blocks/CU (LDS-capped) = 24 waves/CU (was 18).
// ---------------------------------------------------------------------------
__global__ __launch_bounds__(192) void conv_fwd_part_k(
    const float* __restrict__ feat, const float* __restrict__ wsrc,
    float* __restrict__ part)
{
  __shared__ __align__(16) float sfeat[8 * PLSZ];
  int tid = threadIdx.x;
  int n = blockIdx.x;
  int s = n & 63;
  int kc = blockIdx.y;
  const float* fbase = feat + ((size_t)n * C_CH + kc * CPB) * HW;
  const float* wbase = wsrc + ((size_t)s * C_CH + kc * CPB) * FT;

  for (int idx = tid; idx < 8 * PLSZ; idx += 192) sfeat[idx] = 0.f;

  int ch_l = tid / 24;
  int row_l = tid - ch_l * 24;
  bool stager = row_l < 18;

  int pos = tid >> 3;
  int slot = tid & 7;
  bool act = pos < 20;
  int cpos = act ? pos : 19;
  int ty = cpos / 5, tx = cpos - (cpos / 5) * 5;

  float acc[5][4];
  #pragma unroll
  for (int r = 0; r < 5; ++r)
    #pragma unroll
    for (int c = 0; c < 4; ++c) acc[r][c] = 0.f;

  const float* plane0 = &sfeat[slot * PLSZ + (5 * ty) * PLW + 4 * tx];
  __syncthreads();

  for (int c0 = 0; c0 < CPB; c0 += 8) {
    if (stager) {
      const float* src = fbase + (size_t)(c0 + ch_l) * HW + row_l * 18;
      float* dst = &sfeat[ch_l * PLSZ + (row_l + 2) * PLW + 2];
      #pragma unroll
      for (int k = 0; k < 9; ++k) {
        float2 v = *(const float2*)(src + 2 * k);
        *(float2*)(dst + 2 * k) = v;
      }
    }
    __syncthreads();

    const float4* wp = (const float4*)(wbase + (size_t)(c0 + slot) * FT);
    float4 w0 = wp[0], w1 = wp[1], w2 = wp[2], w3 = wp[3];

    #pragma unroll
    for (int ri = 0; ri < 8; ++ri) {
      float4 ra = *(const float4*)(plane0 + ri * PLW);
      float4 rb = *(const float4*)(plane0 + ri * PLW + 4);
      #pragma unroll
      for (int dy = 0; dy < 4; ++dy) {
        int r = ri - dy;
        if (r < 0 || r > 4) continue;
        float4 wr = (dy == 0) ? w0 : (dy == 1) ? w1 : (dy == 2) ? w2 : w3;
        acc[r][0] = fmaf(ra.x, wr.x, acc[r][0]); acc[r][0] = fmaf(ra.y, wr.y, acc[r][0]);
        acc[r][0] = fmaf(ra.z, wr.z, acc[r][0]); acc[r][0] = fmaf(ra.w, wr.w, acc[r][0]);
        acc[r][1] = fmaf(ra.y, wr.x, acc[r][1]); acc[r][1] = fmaf(ra.z, wr.y, acc[r][1]);
        acc[r][1] = fmaf(ra.w, wr.z, acc[r][1]); acc[r][1] = fmaf(rb.x, wr.w, acc[r][1]);
        acc[r][2] = fmaf(ra.z, wr.x, acc[r][2]); acc[r][2] = fmaf(ra.w, wr.y, acc[r][2]);
        acc[r][2] = fmaf(rb.x, wr.z, acc[r][2]); acc[r][2] = fmaf(rb.y, wr.w, acc[r][2]);
        acc[r][3] = fmaf(ra.w, wr.x, acc[r][3]); acc[r][3] = fmaf(rb.x, wr.y, acc[r][3]);
        acc[r][3] = fmaf(rb.y, wr.z, acc[r][3]); acc[r][3] = fmaf(rb.z, wr.w, acc[r][3]);
      }
    }
    __syncthreads();
  }

  #pragma unroll
  for (int r = 0; r < 5; ++r)
    #pragma unroll
    for (int c = 0; c < 4; ++c) {
      float v = acc[r][c];
      v += __shfl_xor(v, 1, 64);
      v += __shfl_xor(v, 2, 64);
      v += __shfl_xor(v, 4, 64);
      acc[r][c] = v;
    }

  int orow = 5 * ty + slot;
  if (act && slot < 5 && orow < OH) {
    float4 v = make_float4(acc[slot][0], acc[slot][1], acc[slot][2], acc[slot][3]);
    *(float4*)(part + ((size_t)n * CSPLIT + kc) * PPIX + orow * 20 + 4 * tx) = v;
  }
}

// ---------------------------------------------------------------------------
// combine0 (once): sum partials -> scores buffer + mask + residuals
// ---------------------------------------------------------------------------
__global__ __launch_bounds__(384) void combine0_k(
    const float* __restrict__ part,
    const float* __restrict__ sw, const float* __restrict__ lm,
    const float* __restrict__ alo, const float* __restrict__ ahi,
    float* __restrict__ scores,
    float* __restrict__ mask, float* __restrict__ rbuf)
{
  int n = blockIdx.x;
  int p = threadIdx.x;
  if (p >= NPIX) return;
  int y = p / OW, x = p - y * OW;
  const float* pb = part + (size_t)n * CSPLIT * PPIX + y * 20 + x;
  float sv = 0.f;
  #pragma unroll
  for (int k = 0; k < CSPLIT; ++k) sv += pb[k * PPIX];
  int idx = n * NPIX + p;
  scores[idx] = sv;
  float lo = alo[idx], hi = ahi[idx], s_w = sw[idx], l_v = lm[idx];
  float sgn = (sv > 0.f) ? 1.f : ((sv < 0.f) ? -1.f : 0.f);
  float actv = lo * fabsf(sv) + hi * sv;
  float msk = lo * sgn + hi;
  mask[idx] = msk;
  rbuf[idx] = msk * s_w * s_w * (actv - l_v);
}

// ---------------------------------------------------------------------------
// transpose conv v2 (R13-proven, unsplit): uint j packs channels (j, j+256).
// grid (6, 64): blockIdx.x = i*2+cq; lane pair covers uint j = cq*128+cp.
// ---------------------------------------------------------------------------
__global__ __launch_bounds__(256) void conv_tr2_k(
    const ushort* __restrict__ featT, const float* __restrict__ r,
    float* __restrict__ wgp)
{
  __shared__ __align__(16) float rp[21 * RPW];
  int tid = threadIdx.x;
  int i = blockIdx.x >> 1;
  int cq = blockIdx.x & 1;
  int s = blockIdx.y;
  int cp = tid >> 1, h = tid & 1;
  int j = cq * 128 + cp;     // uint slot; channels (j, j+256)

  for (int idx = tid; idx < 21 * RPW; idx += 256) rp[idx] = 0.f;
  __syncthreads();
  for (int idx = tid; idx < NPIX; idx += 256) {
    int y = idx / OW, x = idx - y * OW;
    rp[(y + 1) * RPW + (x + 1)] = r[(size_t)(i * S_SEQ + s) * NPIX + idx];
  }
  __syncthreads();

  float acc0[FT], acc1[FT];
  #pragma unroll
  for (int t = 0; t < FT; ++t) { acc0[t] = 0.f; acc1[t] = 0.f; }

  const uint* fbu = (const uint*)featT + (size_t)(i * S_SEQ + s) * HW * (C_CH / 2)
                    + j;

  for (int uu = 0; uu < 9; ++uu) {
    int u = h * 9 + uu;
    float rw[4][24];
    #pragma unroll
    for (int dy = 0; dy < 4; ++dy) {
      const float4* rr = (const float4*)&rp[(u + 3 - dy) * RPW];
      #pragma unroll
      for (int q = 0; q < 6; ++q) {
        float4 v = rr[q];
        rw[dy][4 * q + 0] = v.x; rw[dy][4 * q + 1] = v.y;
        rw[dy][4 * q + 2] = v.z; rw[dy][4 * q + 3] = v.w;
      }
    }
    uint fv[18];
    #pragma unroll
    for (int v = 0; v < 18; ++v)
      fv[v] = fbu[(size_t)(u * 18 + v) * (C_CH / 2)];
    #pragma unroll
    for (int v = 0; v < 18; ++v) {
      float f0 = __uint_as_float(fv[v] << 16);
      float f1 = __uint_as_float(fv[v] & 0xffff0000u);
      #pragma unroll
      for (int dy = 0; dy < 4; ++dy) {
        #pragma unroll
        for (int dx = 0; dx < 4; ++dx) {
          acc0[dy * 4 + dx] = fmaf(f0, rw[dy][v + 3 - dx], acc0[dy * 4 + dx]);
          acc1[dy * 4 + dx] = fmaf(f1, rw[dy][v + 3 - dx], acc1[dy * 4 + dx]);
        }
      }
    }
  }

  #pragma unroll
  for (int t = 0; t < FT; ++t) {
    acc0[t] += __shfl_xor(acc0[t], 1, 64);
    acc1[t] += __shfl_xor(acc1[t], 1, 64);
  }

  float out[FT];
  #pragma unroll
  for (int t = 0; t < FT; ++t) out[t] = h ? acc1[t] : acc0[t];
  int c = j + h * 256;
  float4* dst = (float4*)(wgp + (((size_t)i * S_SEQ + s) * C_CH + c) * FT);
  dst[0] = make_float4(out[0], out[1], out[2], out[3]);
  dst[1] = make_float4(out[4], out[5], out[6], out[7]);
  dst[2] = make_float4(out[8], out[9], out[10], out[11]);
  dst[3] = make_float4(out[12], out[13], out[14], out[15]);
}

// ---------------------------------------------------------------------------
// combine_wg: wg = sum_i wgp + reg*wcur; nump[s] = ||wg||^2
// ---------------------------------------------------------------------------
__global__ __launch_bounds__(256) void combine_wg_k(
    const float* __restrict__ wgp, const float* __restrict__ wcur,
    const float* __restrict__ scal,
    float* __restrict__ wg, float* __restrict__ nump)
{
  __shared__ float rtmp[4];
  int s = blockIdx.x;
  int tid = threadIdx.x;
  float regv = scal[1];
  size_t base = (size_t)s * C_CH * FT;
  size_t istr = (size_t)S_SEQ * C_CH * FT;
  const float4* p0 = (const float4*)(wgp + base);
  const float4* p1 = (const float4*)(wgp + istr + base);
  const float4* p2 = (const float4*)(wgp + 2 * istr + base);
  const float4* pw = (const float4*)(wcur + base);
  float4* pg = (float4*)(wg + base);
  float sq = 0.f;
  for (int g = tid; g < C_CH * FT / 4; g += 256) {
    float4 a = p0[g], b = p1[g], c = p2[g], w = pw[g];
    float4 v;
    v.x = a.x + b.x + c.x + regv * w.x;
    v.y = a.y + b.y + c.y + regv * w.y;
    v.z = a.z + b.z + c.z + regv * w.z;
    v.w = a.w + b.w + c.w + regv * w.w;
    pg[g] = v;
    sq += v.x * v.x + v.y * v.y + v.z * v.z + v.w * v.w;
  }
  float tot = blk_reduce(sq, rtmp);
  if (tid == 0) nump[s] = tot;
}

// ---------------------------------------------------------------------------
// update: den from sg partials, alpha, weight step, incremental scores update,
// next-iteration mask/residuals.
// ---------------------------------------------------------------------------
__global__ __launch_bounds__(256) void update_k(
    float* __restrict__ wcur, const float* __restrict__ wg,
    const float* __restrict__ partb,
    const float* __restrict__ sw, const float* __restrict__ lm,
    const float* __restrict__ alo, const float* __restrict__ ahi,
    float* __restrict__ scores, float* __restrict__ mask,
    float* __restrict__ rbuf,
    const float* __restrict__ nump, const float* __restrict__ scal)
{
  __shared__ float rtmp[4];
  __shared__ float s_sa;
  int s = blockIdx.x;
  int tid = threadIdx.x;

  float sgl[5];
  float sq = 0.f;
  #pragma unroll
  for (int k = 0; k < 5; ++k) {
    int g = tid + k * 256;
    sgl[k] = 0.f;
    if (g < I_IMG * NPIX) {
      int i = g / NPIX, p = g - i * NPIX;
      int n = i * S_SEQ + s;
      int y = p / OW, x = p - y * OW;
      const float* pb = partb + (size_t)n * CSPLIT * PPIX + y * 20 + x;
      float sv = 0.f;
      #pragma unroll
      for (int kk = 0; kk < CSPLIT; ++kk) sv += pb[kk * PPIX];
      sgl[k] = sv;
      int idx = n * NPIX + p;
      float sg = sw[idx] * mask[idx] * sv;
      sq += sg * sg;
    }
  }
  float den = blk_reduce(sq, rtmp);
  if (tid == 0) {
    float num = nump[s];
    float regv = scal[1], step = scal[0];
    float d = fmaxf(den + regv * num, 1e-8f);
    s_sa = step * (num / d);
  }
  __syncthreads();
  float sa = s_sa;

  float4* w4 = (float4*)(wcur + (size_t)s * (C_CH * FT));
  const float4* g4 = (const float4*)(wg + (size_t)s * (C_CH * FT));
  for (int idx = tid; idx < C_CH * FT / 4; idx += 256) {
    float4 w = w4[idx], g = g4[idx];
    w.x -= sa * g.x; w.y -= sa * g.y; w.z -= sa * g.z; w.w -= sa * g.w;
    w4[idx] = w;
  }

  #pragma unroll
  for (int k = 0; k < 5; ++k) {
    int g = tid + k * 256;
    if (g < I_IMG * NPIX) {
      int i = g / NPIX, p = g - i * NPIX;
      int idx = (i * S_SEQ + s) * NPIX + p;
      float sv = scores[idx] - sa * sgl[k];
      scores[idx] = sv;
      float lo = alo[idx], hi = ahi[idx], s_w = sw[idx], l_v = lm[idx];
      float sgn = (sv > 0.f) ? 1.f : ((sv < 0.f) ? -1.f : 0.f);
      float actv = lo * fabsf(sv) + hi * sv;
      float msk = lo * sgn + hi;
      mask[idx] = msk;
      rbuf[idx] = msk * s_w * s_w * (actv - l_v);
    }
  }
}

// ---------------------------------------------------------------------------
extern "C" void kernel_launch(void* const* d_in, const int* in_sizes, int n_in,
                              void* d_out, int out_size, void* d_ws, size_t ws_size,
                              hipStream_t stream)
{
  const float* w_in = (const float*)d_in[0];
  const float* feat = (const float*)d_in[1];
  const float* bb   = (const float*)d_in[2];
  const float* lblw = (const float*)d_in[3];
  const float* mskw = (const float*)d_in[4];
  const float* spw  = (const float*)d_in[5];
  const float* lsl  = (const float*)d_in[6];
  const float* freg = (const float*)d_in[7];

  float* base = (float*)d_ws;
  const int NMAP = I_IMG * S_SEQ * NPIX;   // 69312
  const int NW   = S_SEQ * C_CH * FT;      // 524288
  float* sw     = base;
  float* lm     = sw + NMAP;
  float* alo    = lm + NMAP;
  float* ahi    = alo + NMAP;
  float* mask   = ahi + NMAP;
  float* rbuf   = mask + NMAP;
  float* scores = rbuf + NMAP;
  float* wcur   = scores + NMAP;
  float* wg     = wcur + NW;
  float* wgp    = wg + NW;                 // 3*NW
  float* nump   = wgp + 3 * NW;
  float* scal   = nump + S_SEQ;
  float* partb  = scal + 8;                // I*S*CSPLIT*PPIX = 1228800
  ushort* featT = (ushort*)(partb + (size_t)I_IMG * S_SEQ * CSPLIT * PPIX);

  convert_k<<<dim3(I_IMG * S_SEQ, 16), 256, 0, stream>>>(feat, featT);
  prep_k<<<I_IMG * S_SEQ, 384, 0, stream>>>(bb, lblw, mskw, spw, lsl, freg,
                                            sw, lm, alo, ahi, scal);
  hipMemcpyAsync(wcur, w_in, (size_t)NW * sizeof(float),
                 hipMemcpyDeviceToDevice, stream);

  // initial scores (only forward conv of wcur)
  conv_fwd_part_k<<<dim3(I_IMG * S_SEQ, CSPLIT), 192, 0, stream>>>(
      feat, wcur, partb);
  combine0_k<<<I_IMG * S_SEQ, 384, 0, stream>>>(
      partb, sw, lm, alo, ahi, scores, mask, rbuf);

  for (int it = 0; it < NITER; ++it) {
    conv_tr2_k<<<dim3(6, S_SEQ), 256, 0, stream>>>(featT, rbuf, wgp);
    combine_wg_k<<<S_SEQ, 256, 0, stream>>>(wgp, wcur, scal, wg, nump);
    conv_fwd_part_k<<<dim3(I_IMG * S_SEQ, CSPLIT), 192, 0, stream>>>(
        feat, wg, partb);
    update_k<<<S_SEQ, 256, 0, stream>>>(
        wcur, wg, partb, sw, lm, alo, ahi, scores, mask, rbuf, nump, scal);
  }
  hipMemcpyAsync(d_out, wcur, (size_t)NW * sizeof(float),
                 hipMemcpyDeviceToDevice, stream);
}

// Round 17
// 477.934 us; speedup vs baseline: 1.1936x; 1.0647x over previous
//
#include <hip/hip_runtime.h>
#include <math.h>

#define I_IMG 3
#define S_SEQ 64
#define C_CH  512
#define H_IN  18
#define W_IN  18
#define HW    324
#define OH 19
#define OW 19
#define NPIX 361
#define FT 16
#define NITER 5
#define RPW 24            // tr rp row stride
#define CVS 32            // uint slots per convert block
#define CVP 162           // pixels per convert block
#define SPL 336           // S plane length (21 tiles x 16)

typedef unsigned int uint;
typedef unsigned short ushort;
typedef float f32x4 __attribute__((ext_vector_type(4)));
typedef short s16x8 __attribute__((ext_vector_type(8)));

__device__ inline float blk_reduce(float v, float* tmp) {
  #pragma unroll
  for (int o = 32; o > 0; o >>= 1) v += __shfl_down(v, o, 64);
  int lane = threadIdx.x & 63;
  int w = threadIdx.x >> 6;
  if (lane == 0) tmp[w] = v;
  __syncthreads();
  float r = 0.f;
  if (threadIdx.x == 0) {
    int nw = (blockDim.x + 63) >> 6;
    for (int k = 0; k < nw; ++k) r += tmp[k];
  }
  return r;
}

__device__ inline uint pack_bf2(float lo, float hi) {  // RNE f32x2 -> packed bf16x2
  uint ul = __float_as_uint(lo);
  uint uh = __float_as_uint(hi);
  ul = (ul + 0x7fffu + ((ul >> 16) & 1u)) >> 16;
  uh = (uh + 0x7fffu + ((uh >> 16) & 1u)) & 0xffff0000u;
  return ul | uh;
}

__device__ inline ushort bf16r(float f) {  // RNE f32 -> bf16
  uint u = __float_as_uint(f);
  return (ushort)((u + 0x7fffu + ((u >> 16) & 1u)) >> 16);
}

// ushort index within featT's packed channel order for natural channel c
__device__ inline int chperm(int c) { return (c < 256) ? 2 * c : 2 * (c - 256) + 1; }

// ---------------------------------------------------------------------------
// convert (R11 exact): feat f32 [n][c][p] -> featT packed-bf16 [n][p][k],
// k ushort index; uint slot j packs channels (j, j+256). grid (192, 16).
// ---------------------------------------------------------------------------
__global__ __launch_bounds__(256) void convert_k(
    const float* __restrict__ feat, ushort* __restrict__ featT)
{
  __shared__ uint tile[CVP * CVS];   // 20736 B
  int tid = threadIdx.x;
  int n = blockIdx.x;
  int yz = blockIdx.y;
  int k0 = (yz >> 1) * CVS;
  int p0 = (yz & 1) * CVP;
  const float* fbase = feat + (size_t)n * C_CH * HW + p0;

  for (int idx = tid; idx < CVS * 81; idx += 256) {
    int k = idx / 81, q = idx - k * 81;
    int j = k0 + k;
    float2 lo = *(const float2*)(fbase + (size_t)j * HW + 2 * q);
    float2 hi = *(const float2*)(fbase + (size_t)(j + 256) * HW + 2 * q);
    uint b = (uint)(2 * q) * CVS + (uint)(k ^ (q & 31));  // XOR bank swizzle
    tile[b] = pack_bf2(lo.x, hi.x);
    tile[b + CVS] = pack_bf2(lo.y, hi.y);
  }
  __syncthreads();

  uint* dTb = (uint*)featT + ((size_t)n * HW + p0) * (C_CH / 2) + k0;
  for (int idx = tid; idx < CVP * CVS; idx += 256) {
    int px = idx >> 5, k = idx & 31;
    dTb[(size_t)px * (C_CH / 2) + k] = tile[px * CVS + (k ^ ((px >> 1) & 31))];
  }
}

// ---------------------------------------------------------------------------
// prep: distance map -> label_map, sample_weight, a_lo, a_hi; scalars
// ---------------------------------------------------------------------------
__global__ void prep_k(const float* __restrict__ bb,
                       const float* __restrict__ label_w,
                       const float* __restrict__ mask_w,
                       const float* __restrict__ spatial_w,
                       const float* __restrict__ lsl,
                       const float* __restrict__ freg,
                       float* __restrict__ sw, float* __restrict__ lm,
                       float* __restrict__ alo, float* __restrict__ ahi,
                       float* __restrict__ scal)
{
  int n = blockIdx.x;
  int p = threadIdx.x;
  if (n == 0 && p == 0) {
    scal[0] = expf(lsl[0]);
    scal[1] = fmaxf(freg[0] * freg[0], 1e-6f);
  }
  if (p >= NPIX) return;
  float bx = bb[n * 4 + 0], by = bb[n * 4 + 1];
  float bw = bb[n * 4 + 2], bh = bb[n * 4 + 3];
  float crow = (by + bh * 0.5f) * (1.f / 16.f);
  float ccol = (bx + bw * 0.5f) * (1.f / 16.f);
  int y = p / OW, x = p - (p / OW) * OW;
  float d0 = (float)y - crow, d1 = (float)x - ccol;
  float dist = sqrtf(d0 * d0 + d1 * d1);
  float bins[5];
  #pragma unroll
  for (int b = 0; b < 4; ++b) bins[b] = fmaxf(1.f - fabsf(dist - (float)b), 0.f);
  bins[4] = fminf(fmaxf(dist - 3.f, 0.f), 1.f);
  float lmv = 0.f, mm = 0.f, sp = 0.f;
  #pragma unroll
  for (int b = 0; b < 5; ++b) {
    lmv += bins[b] * label_w[b];
    mm  += bins[b] * mask_w[b];
    sp  += bins[b] * spatial_w[b];
  }
  float tm = 1.f / (1.f + expf(-mm));
  int idx = n * NPIX + p;
  lm[idx]  = lmv;
  sw[idx]  = 0.57735026918962584f * sp;
  alo[idx] = 0.5f * (1.f - tm);
  ahi[idx] = 0.5f * (1.f + tm);
}

// ---------------------------------------------------------------------------
// wT_k: w fp32 [s][c][16] -> wTb bf16 [s][t][512] (featT channel order)
// ---------------------------------------------------------------------------
__global__ __launch_bounds__(256) void wT_k(
    const float* __restrict__ w, ushort* __restrict__ wTb)
{
  int s = blockIdx.x;
  const float4* pw = (const float4*)(w + (size_t)s * C_CH * FT);
  ushort* wb = wTb + (size_t)s * 16 * 512;
  for (int g = threadIdx.x; g < C_CH * FT / 4; g += 256) {
    int c = g >> 2, tq = (g & 3) * 4;
    float4 v = pw[g];
    int k = chperm(c);
    wb[(tq + 0) * 512 + k] = bf16r(v.x);
    wb[(tq + 1) * 512 + k] = bf16r(v.y);
    wb[(tq + 2) * 512 + k] = bf16r(v.z);
    wb[(tq + 3) * 512 + k] = bf16r(v.w);
  }
}

// ---------------------------------------------------------------------------
// mfma_fwd: S[n][t][p] = sum_c featT[n][p][c] * wTb[s][t][c]
// grid (192, 6) x 256; wave = one 16-pixel M-tile; 16 K-steps of 16x16x32.
// ---------------------------------------------------------------------------
__global__ __launch_bounds__(256) void mfma_fwd_k(
    const ushort* __restrict__ featT, const ushort* __restrict__ wTb,
    float* __restrict__ S)
{
  int lane = threadIdx.x & 63;
  int wv = threadIdx.x >> 6;
  int n = blockIdx.x;
  int s = n & 63;
  int mtile = blockIdx.y * 4 + wv;
  if (mtile >= 21) return;
  int mrow = lane & 15;       // A row (pixel in tile) / B col (tap) / D col (tap)
  int kg = lane >> 4;         // k-group

  // B frags: wTb[s][tap=mrow][k0*32 + kg*8 .. +7]
  const ushort* wb = wTb + ((size_t)s * 16 + mrow) * 512 + kg * 8;
  s16x8 bfrag[16];
  #pragma unroll
  for (int k0 = 0; k0 < 16; ++k0)
    bfrag[k0] = *(const s16x8*)(wb + k0 * 32);

  int p = mtile * 16 + mrow;
  bool pvalid = p < HW;
  const ushort* fa = featT + ((size_t)n * HW + (pvalid ? p : 0)) * 512 + kg * 8;
  s16x8 zero8 = {0, 0, 0, 0, 0, 0, 0, 0};

  f32x4 acc = {0.f, 0.f, 0.f, 0.f};
  #pragma unroll
  for (int k0 = 0; k0 < 16; ++k0) {
    s16x8 afrag = pvalid ? *(const s16x8*)(fa + k0 * 32) : zero8;
    acc = __builtin_amdgcn_mfma_f32_16x16x32_bf16(afrag, bfrag[k0], acc, 0, 0, 0);
  }

  // D: col = mrow (tap), rows = kg*4 + 0..3 (pixel in tile)
  float* dst = S + ((size_t)n * 16 + mrow) * SPL + mtile * 16 + kg * 4;
  *(float4*)dst = make_float4(acc[0], acc[1], acc[2], acc[3]);
}

// ---------------------------------------------------------------------------
// gather scores from S planes: scores[yo][xo] = sum_t S[t][yo+dy-2][xo+dx-2]
// ---------------------------------------------------------------------------
__device__ inline float s_gather(const float* __restrict__ Sp, int yo, int xo) {
  float sv = 0.f;
  #pragma unroll
  for (int dy = 0; dy < 4; ++dy) {
    int yi = yo + dy - 2;
    if (yi < 0 || yi >= H_IN) continue;
    #pragma unroll
    for (int dx = 0; dx < 4; ++dx) {
      int xi = xo + dx - 2;
      if (xi < 0 || xi >= W_IN) continue;
      sv += Sp[(dy * 4 + dx) * SPL + yi * W_IN + xi];
    }
  }
  return sv;
}

// ---------------------------------------------------------------------------
// combine0 (once): S -> scores + mask + residuals
// ---------------------------------------------------------------------------
__global__ __launch_bounds__(384) void combine0_k(
    const float* __restrict__ S,
    const float* __restrict__ sw, const float* __restrict__ lm,
    const float* __restrict__ alo, const float* __restrict__ ahi,
    float* __restrict__ scores,
    float* __restrict__ mask, float* __restrict__ rbuf)
{
  int n = blockIdx.x;
  int p = threadIdx.x;
  if (p >= NPIX) return;
  int yo = p / OW, xo = p - yo * OW;
  float sv = s_gather(S + (size_t)n * 16 * SPL, yo, xo);
  int idx = n * NPIX + p;
  scores[idx] = sv;
  float lo = alo[idx], hi = ahi[idx], s_w = sw[idx], l_v = lm[idx];
  float sgn = (sv > 0.f) ? 1.f : ((sv < 0.f) ? -1.f : 0.f);
  float actv = lo * fabsf(sv) + hi * sv;
  float msk = lo * sgn + hi;
  mask[idx] = msk;
  rbuf[idx] = msk * s_w * s_w * (actv - l_v);
}

// ---------------------------------------------------------------------------
// transpose conv v2 (unchanged): uint j packs channels (j, j+256).
// ---------------------------------------------------------------------------
__global__ __launch_bounds__(256) void conv_tr2_k(
    const ushort* __restrict__ featT, const float* __restrict__ r,
    float* __restrict__ wgp)
{
  __shared__ __align__(16) float rp[21 * RPW];
  int tid = threadIdx.x;
  int i = blockIdx.x >> 1;
  int cq = blockIdx.x & 1;
  int s = blockIdx.y;
  int cp = tid >> 1, h = tid & 1;
  int j = cq * 128 + cp;

  for (int idx = tid; idx < 21 * RPW; idx += 256) rp[idx] = 0.f;
  __syncthreads();
  for (int idx = tid; idx < NPIX; idx += 256) {
    int y = idx / OW, x = idx - y * OW;
    rp[(y + 1) * RPW + (x + 1)] = r[(size_t)(i * S_SEQ + s) * NPIX + idx];
  }
  __syncthreads();

  float acc0[FT], acc1[FT];
  #pragma unroll
  for (int t = 0; t < FT; ++t) { acc0[t] = 0.f; acc1[t] = 0.f; }

  const uint* fbu = (const uint*)featT + (size_t)(i * S_SEQ + s) * HW * (C_CH / 2)
                    + j;

  for (int uu = 0; uu < 9; ++uu) {
    int u = h * 9 + uu;
    float rw[4][24];
    #pragma unroll
    for (int dy = 0; dy < 4; ++dy) {
      const float4* rr = (const float4*)&rp[(u + 3 - dy) * RPW];
      #pragma unroll
      for (int q = 0; q < 6; ++q) {
        float4 v = rr[q];
        rw[dy][4 * q + 0] = v.x; rw[dy][4 * q + 1] = v.y;
        rw[dy][4 * q + 2] = v.z; rw[dy][4 * q + 3] = v.w;
      }
    }
    uint fv[18];
    #pragma unroll
    for (int v = 0; v < 18; ++v)
      fv[v] = fbu[(size_t)(u * 18 + v) * (C_CH / 2)];
    #pragma unroll
    for (int v = 0; v < 18; ++v) {
      float f0 = __uint_as_float(fv[v] << 16);
      float f1 = __uint_as_float(fv[v] & 0xffff0000u);
      #pragma unroll
      for (int dy = 0; dy < 4; ++dy) {
        #pragma unroll
        for (int dx = 0; dx < 4; ++dx) {
          acc0[dy * 4 + dx] = fmaf(f0, rw[dy][v + 3 - dx], acc0[dy * 4 + dx]);
          acc1[dy * 4 + dx] = fmaf(f1, rw[dy][v + 3 - dx], acc1[dy * 4 + dx]);
        }
      }
    }
  }

  #pragma unroll
  for (int t = 0; t < FT; ++t) {
    acc0[t] += __shfl_xor(acc0[t], 1, 64);
    acc1[t] += __shfl_xor(acc1[t], 1, 64);
  }

  float out[FT];
  #pragma unroll
  for (int t = 0; t < FT; ++t) out[t] = h ? acc1[t] : acc0[t];
  int c = j + h * 256;
  float4* dst = (float4*)(wgp + (((size_t)i * S_SEQ + s) * C_CH + c) * FT);
  dst[0] = make_float4(out[0], out[1], out[2], out[3]);
  dst[1] = make_float4(out[4], out[5], out[6], out[7]);
  dst[2] = make_float4(out[8], out[9], out[10], out[11]);
  dst[3] = make_float4(out[12], out[13], out[14], out[15]);
}

// ---------------------------------------------------------------------------
// combine_wg: wg = sum_i wgp + reg*wcur (fp32) + wgTb bf16 [s][t][512];
// nump[s] = ||wg||^2
// ---------------------------------------------------------------------------
__global__ __launch_bounds__(256) void combine_wg_k(
    const float* __restrict__ wgp, const float* __restrict__ wcur,
    const float* __restrict__ scal,
    float* __restrict__ wg, ushort* __restrict__ wgTb,
    float* __restrict__ nump)
{
  __shared__ float rtmp[4];
  int s = blockIdx.x;
  int tid = threadIdx.x;
  float regv = scal[1];
  size_t base = (size_t)s * C_CH * FT;
  size_t istr = (size_t)S_SEQ * C_CH * FT;
  const float4* p0 = (const float4*)(wgp + base);
  const float4* p1 = (const float4*)(wgp + istr + base);
  const float4* p2 = (const float4*)(wgp + 2 * istr + base);
  const float4* pw = (const float4*)(wcur + base);
  float4* pg = (float4*)(wg + base);
  ushort* wb = wgTb + (size_t)s * 16 * 512;
  float sq = 0.f;
  for (int g = tid; g < C_CH * FT / 4; g += 256) {
    float4 a = p0[g], b = p1[g], c = p2[g], w = pw[g];
    float4 v;
    v.x = a.x + b.x + c.x + regv * w.x;
    v.y = a.y + b.y + c.y + regv * w.y;
    v.z = a.z + b.z + c.z + regv * w.z;
    v.w = a.w + b.w + c.w + regv * w.w;
    pg[g] = v;
    sq += v.x * v.x + v.y * v.y + v.z * v.z + v.w * v.w;
    int ch = g >> 2, tq = (g & 3) * 4;
    int k = chperm(ch);
    wb[(tq + 0) * 512 + k] = bf16r(v.x);
    wb[(tq + 1) * 512 + k] = bf16r(v.y);
    wb[(tq + 2) * 512 + k] = bf16r(v.z);
    wb[(tq + 3) * 512 + k] = bf16r(v.w);
  }
  float tot = blk_reduce(sq, rtmp);
  if (tid == 0) nump[s] = tot;
}

// ---------------------------------------------------------------------------
// update: den from S-gathered sg, alpha, weight step, incremental scores,
// next mask/residuals.
// ---------------------------------------------------------------------------
__global__ __launch_bounds__(256) void update_k(
    float* __restrict__ wcur, const float* __restrict__ wg,
    const float* __restrict__ S,
    const float* __restrict__ sw, const float* __restrict__ lm,
    const float* __restrict__ alo, const float* __restrict__ ahi,
    float* __restrict__ scores, float* __restrict__ mask,
    float* __restrict__ rbuf,
    const float* __restrict__ nump, const float* __restrict__ scal)
{
  __shared__ float rtmp[4];
  __shared__ float s_sa;
  int s = blockIdx.x;
  int tid = threadIdx.x;

  float sgl[5];
  float sq = 0.f;
  #pragma unroll
  for (int k = 0; k < 5; ++k) {
    int g = tid + k * 256;
    sgl[k] = 0.f;
    if (g < I_IMG * NPIX) {
      int i = g / NPIX, p = g - i * NPIX;
      int n = i * S_SEQ + s;
      int yo = p / OW, xo = p - yo * OW;
      float sv = s_gather(S + (size_t)n * 16 * SPL, yo, xo);
      sgl[k] = sv;
      int idx = n * NPIX + p;
      float sg = sw[idx] * mask[idx] * sv;
      sq += sg * sg;
    }
  }
  float den = blk_reduce(sq, rtmp);
  if (tid == 0) {
    float num = nump[s];
    float regv = scal[1], step = scal[0];
    float d = fmaxf(den + regv * num, 1e-8f);
    s_sa = step * (num / d);
  }
  __syncthreads();
  float sa = s_sa;

  float4* w4 = (float4*)(wcur + (size_t)s * (C_CH * FT));
  const float4* g4 = (const float4*)(wg + (size_t)s * (C_CH * FT));
  for (int idx = tid; idx < C_CH * FT / 4; idx += 256) {
    float4 w = w4[idx], g = g4[idx];
    w.x -= sa * g.x; w.y -= sa * g.y; w.z -= sa * g.z; w.w -= sa * g.w;
    w4[idx] = w;
  }

  #pragma unroll
  for (int k = 0; k < 5; ++k) {
    int g = tid + k * 256;
    if (g < I_IMG * NPIX) {
      int i = g / NPIX, p = g - i * NPIX;
      int idx = (i * S_SEQ + s) * NPIX + p;
      float sv = scores[idx] - sa * sgl[k];
      scores[idx] = sv;
      float lo = alo[idx], hi = ahi[idx], s_w = sw[idx], l_v = lm[idx];
      float sgn = (sv > 0.f) ? 1.f : ((sv < 0.f) ? -1.f : 0.f);
      float actv = lo * fabsf(sv) + hi * sv;
      float msk = lo * sgn + hi;
      mask[idx] = msk;
      rbuf[idx] = msk * s_w * s_w * (actv - l_v);
    }
  }
}

// ---------------------------------------------------------------------------
extern "C" void kernel_launch(void* const* d_in, const int* in_sizes, int n_in,
                              void* d_out, int out_size, void* d_ws, size_t ws_size,
                              hipStream_t stream)
{
  const float* w_in = (const float*)d_in[0];
  const float* feat = (const float*)d_in[1];
  const float* bb   = (const float*)d_in[2];
  const float* lblw = (const float*)d_in[3];
  const float* mskw = (const float*)d_in[4];
  const float* spw  = (const float*)d_in[5];
  const float* lsl  = (const float*)d_in[6];
  const float* freg = (const float*)d_in[7];

  float* base = (float*)d_ws;
  const int NMAP = I_IMG * S_SEQ * NPIX;   // 69312
  const int NW   = S_SEQ * C_CH * FT;      // 524288
  float* sw     = base;
  float* lm     = sw + NMAP;
  float* alo    = lm + NMAP;
  float* ahi    = alo + NMAP;
  float* mask   = ahi + NMAP;
  float* rbuf   = mask + NMAP;
  float* scores = rbuf + NMAP;
  float* wcur   = scores + NMAP;
  float* wg     = wcur + NW;
  float* wgp    = wg + NW;                 // 3*NW
  float* nump   = wgp + 3 * NW;
  float* scal   = nump + S_SEQ;
  float* Sbuf   = scal + 8;                // 192*16*336 = 1032192
  ushort* wTb   = (ushort*)(Sbuf + (size_t)I_IMG * S_SEQ * 16 * SPL);
  ushort* featT = wTb + (size_t)S_SEQ * 16 * 512;

  convert_k<<<dim3(I_IMG * S_SEQ, 16), 256, 0, stream>>>(feat, featT);
  prep_k<<<I_IMG * S_SEQ, 384, 0, stream>>>(bb, lblw, mskw, spw, lsl, freg,
                                            sw, lm, alo, ahi, scal);
  hipMemcpyAsync(wcur, w_in, (size_t)NW * sizeof(float),
                 hipMemcpyDeviceToDevice, stream);

  // initial scores via MFMA GEMM
  wT_k<<<S_SEQ, 256, 0, stream>>>(wcur, wTb);
  mfma_fwd_k<<<dim3(I_IMG * S_SEQ, 6), 256, 0, stream>>>(featT, wTb, Sbuf);
  combine0_k<<<I_IMG * S_SEQ, 384, 0, stream>>>(
      Sbuf, sw, lm, alo, ahi, scores, mask, rbuf);

  for (int it = 0; it < NITER; ++it) {
    conv_tr2_k<<<dim3(6, S_SEQ), 256, 0, stream>>>(featT, rbuf, wgp);
    combine_wg_k<<<S_SEQ, 256, 0, stream>>>(wgp, wcur, scal, wg, wTb, nump);
    mfma_fwd_k<<<dim3(I_IMG * S_SEQ, 6), 256, 0, stream>>>(featT, wTb, Sbuf);
    update_k<<<S_SEQ, 256, 0, stream>>>(
        wcur, wg, Sbuf, sw, lm, alo, ahi, scores, mask, rbuf, nump, scal);
  }
  hipMemcpyAsync(d_out, wcur, (size_t)NW * sizeof(float),
                 hipMemcpyDeviceToDevice, stream);
}

// Round 18
// 472.453 us; speedup vs baseline: 1.2075x; 1.0116x over previous
//
#include <hip/hip_runtime.h>
#include <math.h>

#define I_IMG 3
#define S_SEQ 64
#define C_CH  512
#define H_IN  18
#define W_IN  18
#define HW    324
#define OH 19
#define OW 19
#define NPIX 361
#define FT 16
#define NITER 5
#define RPW 24            // tr rp row stride
#define CVS 32            // uint slots per convert block
#define CVP 162           // pixels per convert block
#define SPL 336           // S plane length (21 tiles x 16)
#define BPL 352           // featB padded plane length (11 x 32)
#define ASTR 360          // A-lds row stride (ushorts): 2-way-free banks

typedef unsigned int uint;
typedef unsigned short ushort;
typedef float f32x4 __attribute__((ext_vector_type(4)));
typedef short s16x8 __attribute__((ext_vector_type(8)));

__device__ inline float blk_reduce(float v, float* tmp) {
  #pragma unroll
  for (int o = 32; o > 0; o >>= 1) v += __shfl_down(v, o, 64);
  int lane = threadIdx.x & 63;
  int w = threadIdx.x >> 6;
  if (lane == 0) tmp[w] = v;
  __syncthreads();
  float r = 0.f;
  if (threadIdx.x == 0) {
    int nw = (blockDim.x + 63) >> 6;
    for (int k = 0; k < nw; ++k) r += tmp[k];
  }
  return r;
}

__device__ inline uint pack_bf2(float lo, float hi) {  // RNE f32x2 -> packed bf16x2
  uint ul = __float_as_uint(lo);
  uint uh = __float_as_uint(hi);
  ul = (ul + 0x7fffu + ((ul >> 16) & 1u)) >> 16;
  uh = (uh + 0x7fffu + ((uh >> 16) & 1u)) & 0xffff0000u;
  return ul | uh;
}

__device__ inline uint pack_bf2_adj(float a, float b) { // (a,b) -> bf16(a)|bf16(b)<<16
  uint ua = __float_as_uint(a);
  uint ub = __float_as_uint(b);
  ua = (ua + 0x7fffu + ((ua >> 16) & 1u)) >> 16;
  ub = (ub + 0x7fffu + ((ub >> 16) & 1u)) & 0xffff0000u;
  return ua | ub;
}

__device__ inline ushort bf16r(float f) {  // RNE f32 -> bf16
  uint u = __float_as_uint(f);
  return (ushort)((u + 0x7fffu + ((u >> 16) & 1u)) >> 16);
}

// ushort index within featT's packed channel order for natural channel c
__device__ inline int chperm(int c) { return (c < 256) ? 2 * c : 2 * (c - 256) + 1; }

// ---------------------------------------------------------------------------
// convert: feat f32 [n][c][p] -> featT packed-bf16 [n][p][k]   (fwd A operand)
//                             -> featB bf16 [n][c][352-padded] (tr  B operand)
// grid (192, 16). Stage loop coalesced; featT via swizzled LDS transpose.
// ---------------------------------------------------------------------------
__global__ __launch_bounds__(256) void convert_k(
    const float* __restrict__ feat, ushort* __restrict__ featT,
    ushort* __restrict__ featB)
{
  __shared__ uint tile[CVP * CVS];   // 20736 B
  int tid = threadIdx.x;
  int n = blockIdx.x;
  int yz = blockIdx.y;
  int k0 = (yz >> 1) * CVS;
  int p0 = (yz & 1) * CVP;
  const float* fbase = feat + (size_t)n * C_CH * HW + p0;

  for (int idx = tid; idx < CVS * 81; idx += 256) {
    int k = idx / 81, q = idx - k * 81;
    int j = k0 + k;
    float2 lo = *(const float2*)(fbase + (size_t)j * HW + 2 * q);
    float2 hi = *(const float2*)(fbase + (size_t)(j + 256) * HW + 2 * q);
    uint b = (uint)(2 * q) * CVS + (uint)(k ^ (q & 31));  // XOR bank swizzle
    tile[b] = pack_bf2(lo.x, hi.x);
    tile[b + CVS] = pack_bf2(lo.y, hi.y);
    // channel-major bf16 copies for the tr GEMM (B operand)
    *(uint*)(featB + ((size_t)n * C_CH + j) * BPL + p0 + 2 * q) =
        pack_bf2_adj(lo.x, lo.y);
    *(uint*)(featB + ((size_t)n * C_CH + j + 256) * BPL + p0 + 2 * q) =
        pack_bf2_adj(hi.x, hi.y);
  }
  // zero featB plane pads (once per channel; done by the p0=162 half-blocks)
  if (yz & 1) {
    for (int idx = tid; idx < 64 * 14; idx += 256) {
      int cc = idx / 14, o = idx - cc * 14;
      int j = k0 + (cc & 31) + (cc >> 5) * 256;
      *(uint*)(featB + ((size_t)n * C_CH + j) * BPL + HW + 2 * o) = 0u;
    }
  }
  __syncthreads();

  uint* dTb = (uint*)featT + ((size_t)n * HW + p0) * (C_CH / 2) + k0;
  for (int idx = tid; idx < CVP * CVS; idx += 256) {
    int px = idx >> 5, k = idx & 31;
    dTb[(size_t)px * (C_CH / 2) + k] = tile[px * CVS + (k ^ ((px >> 1) & 31))];
  }
}

// ---------------------------------------------------------------------------
// prep: distance map -> label_map, sample_weight, a_lo, a_hi; scalars
// ---------------------------------------------------------------------------
__global__ void prep_k(const float* __restrict__ bb,
                       const float* __restrict__ label_w,
                       const float* __restrict__ mask_w,
                       const float* __restrict__ spatial_w,
                       const float* __restrict__ lsl,
                       const float* __restrict__ freg,
                       float* __restrict__ sw, float* __restrict__ lm,
                       float* __restrict__ alo, float* __restrict__ ahi,
                       float* __restrict__ scal)
{
  int n = blockIdx.x;
  int p = threadIdx.x;
  if (n == 0 && p == 0) {
    scal[0] = expf(lsl[0]);
    scal[1] = fmaxf(freg[0] * freg[0], 1e-6f);
  }
  if (p >= NPIX) return;
  float bx = bb[n * 4 + 0], by = bb[n * 4 + 1];
  float bw = bb[n * 4 + 2], bh = bb[n * 4 + 3];
  float crow = (by + bh * 0.5f) * (1.f / 16.f);
  float ccol = (bx + bw * 0.5f) * (1.f / 16.f);
  int y = p / OW, x = p - (p / OW) * OW;
  float d0 = (float)y - crow, d1 = (float)x - ccol;
  float dist = sqrtf(d0 * d0 + d1 * d1);
  float bins[5];
  #pragma unroll
  for (int b = 0; b < 4; ++b) bins[b] = fmaxf(1.f - fabsf(dist - (float)b), 0.f);
  bins[4] = fminf(fmaxf(dist - 3.f, 0.f), 1.f);
  float lmv = 0.f, mm = 0.f, sp = 0.f;
  #pragma unroll
  for (int b = 0; b < 5; ++b) {
    lmv += bins[b] * label_w[b];
    mm  += bins[b] * mask_w[b];
    sp  += bins[b] * spatial_w[b];
  }
  float tm = 1.f / (1.f + expf(-mm));
  int idx = n * NPIX + p;
  lm[idx]  = lmv;
  sw[idx]  = 0.57735026918962584f * sp;
  alo[idx] = 0.5f * (1.f - tm);
  ahi[idx] = 0.5f * (1.f + tm);
}

// ---------------------------------------------------------------------------
// wT_k: w fp32 [s][c][16] -> wTb bf16 [s][t][512] (featT channel order)
// ---------------------------------------------------------------------------
__global__ __launch_bounds__(256) void wT_k(
    const float* __restrict__ w, ushort* __restrict__ wTb)
{
  int s = blockIdx.x;
  const float4* pw = (const float4*)(w + (size_t)s * C_CH * FT);
  ushort* wb = wTb + (size_t)s * 16 * 512;
  for (int g = threadIdx.x; g < C_CH * FT / 4; g += 256) {
    int c = g >> 2, tq = (g & 3) * 4;
    float4 v = pw[g];
    int k = chperm(c);
    wb[(tq + 0) * 512 + k] = bf16r(v.x);
    wb[(tq + 1) * 512 + k] = bf16r(v.y);
    wb[(tq + 2) * 512 + k] = bf16r(v.z);
    wb[(tq + 3) * 512 + k] = bf16r(v.w);
  }
}

// ---------------------------------------------------------------------------
// mfma_fwd (R17-proven): S[n][t][p] = sum_c featT[n][p][c] * wTb[s][t][c]
// ---------------------------------------------------------------------------
__global__ __launch_bounds__(256) void mfma_fwd_k(
    const ushort* __restrict__ featT, const ushort* __restrict__ wTb,
    float* __restrict__ S)
{
  int lane = threadIdx.x & 63;
  int wv = threadIdx.x >> 6;
  int n = blockIdx.x;
  int s = n & 63;
  int mtile = blockIdx.y * 4 + wv;
  if (mtile >= 21) return;
  int mrow = lane & 15;
  int kg = lane >> 4;

  const ushort* wb = wTb + ((size_t)s * 16 + mrow) * 512 + kg * 8;
  s16x8 bfrag[16];
  #pragma unroll
  for (int k0 = 0; k0 < 16; ++k0)
    bfrag[k0] = *(const s16x8*)(wb + k0 * 32);

  int p = mtile * 16 + mrow;
  bool pvalid = p < HW;
  const ushort* fa = featT + ((size_t)n * HW + (pvalid ? p : 0)) * 512 + kg * 8;
  s16x8 zero8 = {0, 0, 0, 0, 0, 0, 0, 0};

  f32x4 acc = {0.f, 0.f, 0.f, 0.f};
  #pragma unroll
  for (int k0 = 0; k0 < 16; ++k0) {
    s16x8 afrag = pvalid ? *(const s16x8*)(fa + k0 * 32) : zero8;
    acc = __builtin_amdgcn_mfma_f32_16x16x32_bf16(afrag, bfrag[k0], acc, 0, 0, 0);
  }

  float* dst = S + ((size_t)n * 16 + mrow) * SPL + mtile * 16 + kg * 4;
  *(float4*)dst = make_float4(acc[0], acc[1], acc[2], acc[3]);
}

// ---------------------------------------------------------------------------
// mfma_tr: wgp[i][s][c][t] = sum_p A[t][p] * featB[(i,s,c)][p]
// A = R^T (bf16, built in LDS from residual plane). grid (6,64) x 256.
// blockIdx.x = i*2 + nh (channel half); wave wv covers 4 n-tiles.
// ---------------------------------------------------------------------------
__global__ __launch_bounds__(256) void mfma_tr_k(
    const ushort* __restrict__ featB, const float* __restrict__ r,
    float* __restrict__ wgp)
{
  __shared__ __align__(16) float rp[21 * RPW];
  __shared__ __align__(16) ushort Ald[16 * ASTR];
  int tid = threadIdx.x;
  int i = blockIdx.x >> 1;
  int nh = blockIdx.x & 1;
  int s = blockIdx.y;

  for (int idx = tid; idx < 21 * RPW; idx += 256) rp[idx] = 0.f;
  __syncthreads();
  for (int idx = tid; idx < NPIX; idx += 256) {
    int y = idx / OW, x = idx - y * OW;
    rp[(y + 1) * RPW + (x + 1)] = r[(size_t)(i * S_SEQ + s) * NPIX + idx];
  }
  __syncthreads();

  // A[t][p] = rp[(u+3-dy)*RPW + (v+3-dx)], t=dy*4+dx, p=u*18+v; pad zeros
  for (int idx = tid; idx < 16 * BPL; idx += 256) {
    int t = idx / BPL, pp = idx - t * BPL;
    ushort val = 0;
    if (pp < HW) {
      int u = pp / 18, vv = pp - u * 18;
      int dy = t >> 2, dx = t & 3;
      val = bf16r(rp[(u + 3 - dy) * RPW + (vv + 3 - dx)]);
    }
    Ald[t * ASTR + pp] = val;
  }
  __syncthreads();

  int lane = tid & 63, wv = tid >> 6;
  int nsub = lane & 15, kg = lane >> 4;

  // A frags (shared across this lane's 4 n-tiles)
  const ushort* arow = Ald + nsub * ASTR + kg * 8;
  s16x8 afr[11];
  #pragma unroll
  for (int ks = 0; ks < 11; ++ks)
    afr[ks] = *(const s16x8*)(arow + ks * 32);

  size_t nsbase = ((size_t)i * S_SEQ + s) * C_CH;
  #pragma unroll
  for (int j = 0; j < 4; ++j) {
    int nt = nh * 16 + wv * 4 + j;
    int c = nt * 16 + nsub;
    const ushort* bb = featB + (nsbase + c) * BPL + kg * 8;
    f32x4 acc = {0.f, 0.f, 0.f, 0.f};
    #pragma unroll
    for (int ks = 0; ks < 11; ++ks) {
      s16x8 bf = *(const s16x8*)(bb + ks * 32);
      acc = __builtin_amdgcn_mfma_f32_16x16x32_bf16(afr[ks], bf, acc, 0, 0, 0);
    }
    float* dst = wgp + (nsbase + c) * FT + kg * 4;
    *(float4*)dst = make_float4(acc[0], acc[1], acc[2], acc[3]);
  }
}

// ---------------------------------------------------------------------------
// gather scores from S planes
// ---------------------------------------------------------------------------
__device__ inline float s_gather(const float* __restrict__ Sp, int yo, int xo) {
  float sv = 0.f;
  #pragma unroll
  for (int dy = 0; dy < 4; ++dy) {
    int yi = yo + dy - 2;
    if (yi < 0 || yi >= H_IN) continue;
    #pragma unroll
    for (int dx = 0; dx < 4; ++dx) {
      int xi = xo + dx - 2;
      if (xi < 0 || xi >= W_IN) continue;
      sv += Sp[(dy * 4 + dx) * SPL + yi * W_IN + xi];
    }
  }
  return sv;
}

// ---------------------------------------------------------------------------
// combine0 (once): S -> scores + mask + residuals
// ---------------------------------------------------------------------------
__global__ __launch_bounds__(384) void combine0_k(
    const float* __restrict__ S,
    const float* __restrict__ sw, const float* __restrict__ lm,
    const float* __restrict__ alo, const float* __restrict__ ahi,
    float* __restrict__ scores,
    float* __restrict__ mask, float* __restrict__ rbuf)
{
  int n = blockIdx.x;
  int p = threadIdx.x;
  if (p >= NPIX) return;
  int yo = p / OW, xo = p - yo * OW;
  float sv = s_gather(S + (size_t)n * 16 * SPL, yo, xo);
  int idx = n * NPIX + p;
  scores[idx] = sv;
  float lo = alo[idx], hi = ahi[idx], s_w = sw[idx], l_v = lm[idx];
  float sgn = (sv > 0.f) ? 1.f : ((sv < 0.f) ? -1.f : 0.f);
  float actv = lo * fabsf(sv) + hi * sv;
  float msk = lo * sgn + hi;
  mask[idx] = msk;
  rbuf[idx] = msk * s_w * s_w * (actv - l_v);
}

// ---------------------------------------------------------------------------
// combine_wg: wg = sum_i wgp + reg*wcur (fp32) + wgTb bf16 [s][t][512];
// nump[s] = ||wg||^2
// ---------------------------------------------------------------------------
__global__ __launch_bounds__(256) void combine_wg_k(
    const float* __restrict__ wgp, const float* __restrict__ wcur,
    const float* __restrict__ scal,
    float* __restrict__ wg, ushort* __restrict__ wgTb,
    float* __restrict__ nump)
{
  __shared__ float rtmp[4];
  int s = blockIdx.x;
  int tid = threadIdx.x;
  float regv = scal[1];
  size_t base = (size_t)s * C_CH * FT;
  size_t istr = (size_t)S_SEQ * C_CH * FT;
  const float4* p0 = (const float4*)(wgp + base);
  const float4* p1 = (const float4*)(wgp + istr + base);
  const float4* p2 = (const float4*)(wgp + 2 * istr + base);
  const float4* pw = (const float4*)(wcur + base);
  float4* pg = (float4*)(wg + base);
  ushort* wb = wgTb + (size_t)s * 16 * 512;
  float sq = 0.f;
  for (int g = tid; g < C_CH * FT / 4; g += 256) {
    float4 a = p0[g], b = p1[g], c = p2[g], w = pw[g];
    float4 v;
    v.x = a.x + b.x + c.x + regv * w.x;
    v.y = a.y + b.y + c.y + regv * w.y;
    v.z = a.z + b.z + c.z + regv * w.z;
    v.w = a.w + b.w + c.w + regv * w.w;
    pg[g] = v;
    sq += v.x * v.x + v.y * v.y + v.z * v.z + v.w * v.w;
    int ch = g >> 2, tq = (g & 3) * 4;
    int k = chperm(ch);
    wb[(tq + 0) * 512 + k] = bf16r(v.x);
    wb[(tq + 1) * 512 + k] = bf16r(v.y);
    wb[(tq + 2) * 512 + k] = bf16r(v.z);
    wb[(tq + 3) * 512 + k] = bf16r(v.w);
  }
  float tot = blk_reduce(sq, rtmp);
  if (tid == 0) nump[s] = tot;
}

// ---------------------------------------------------------------------------
// update: den from S-gathered sg, alpha, weight step, incremental scores,
// next mask/residuals.
// ---------------------------------------------------------------------------
__global__ __launch_bounds__(256) void update_k(
    float* __restrict__ wcur, const float* __restrict__ wg,
    const float* __restrict__ S,
    const float* __restrict__ sw, const float* __restrict__ lm,
    const float* __restrict__ alo, const float* __restrict__ ahi,
    float* __restrict__ scores, float* __restrict__ mask,
    float* __restrict__ rbuf,
    const float* __restrict__ nump, const float* __restrict__ scal)
{
  __shared__ float rtmp[4];
  __shared__ float s_sa;
  int s = blockIdx.x;
  int tid = threadIdx.x;

  float sgl[5];
  float sq = 0.f;
  #pragma unroll
  for (int k = 0; k < 5; ++k) {
    int g = tid + k * 256;
    sgl[k] = 0.f;
    if (g < I_IMG * NPIX) {
      int i = g / NPIX, p = g - i * NPIX;
      int n = i * S_SEQ + s;
      int yo = p / OW, xo = p - yo * OW;
      float sv = s_gather(S + (size_t)n * 16 * SPL, yo, xo);
      sgl[k] = sv;
      int idx = n * NPIX + p;
      float sg = sw[idx] * mask[idx] * sv;
      sq += sg * sg;
    }
  }
  float den = blk_reduce(sq, rtmp);
  if (tid == 0) {
    float num = nump[s];
    float regv = scal[1], step = scal[0];
    float d = fmaxf(den + regv * num, 1e-8f);
    s_sa = step * (num / d);
  }
  __syncthreads();
  float sa = s_sa;

  float4* w4 = (float4*)(wcur + (size_t)s * (C_CH * FT));
  const float4* g4 = (const float4*)(wg + (size_t)s * (C_CH * FT));
  for (int idx = tid; idx < C_CH * FT / 4; idx += 256) {
    float4 w = w4[idx], g = g4[idx];
    w.x -= sa * g.x; w.y -= sa * g.y; w.z -= sa * g.z; w.w -= sa * g.w;
    w4[idx] = w;
  }

  #pragma unroll
  for (int k = 0; k < 5; ++k) {
    int g = tid + k * 256;
    if (g < I_IMG * NPIX) {
      int i = g / NPIX, p = g - i * NPIX;
      int idx = (i * S_SEQ + s) * NPIX + p;
      float sv = scores[idx] - sa * sgl[k];
      scores[idx] = sv;
      float lo = alo[idx], hi = ahi[idx], s_w = sw[idx], l_v = lm[idx];
      float sgn = (sv > 0.f) ? 1.f : ((sv < 0.f) ? -1.f : 0.f);
      float actv = lo * fabsf(sv) + hi * sv;
      float msk = lo * sgn + hi;
      mask[idx] = msk;
      rbuf[idx] = msk * s_w * s_w * (actv - l_v);
    }
  }
}

// ---------------------------------------------------------------------------
extern "C" void kernel_launch(void* const* d_in, const int* in_sizes, int n_in,
                              void* d_out, int out_size, void* d_ws, size_t ws_size,
                              hipStream_t stream)
{
  const float* w_in = (const float*)d_in[0];
  const float* feat = (const float*)d_in[1];
  const float* bb   = (const float*)d_in[2];
  const float* lblw = (const float*)d_in[3];
  const float* mskw = (const float*)d_in[4];
  const float* spw  = (const float*)d_in[5];
  const float* lsl  = (const float*)d_in[6];
  const float* freg = (const float*)d_in[7];

  float* base = (float*)d_ws;
  const int NMAP = I_IMG * S_SEQ * NPIX;   // 69312
  const int NW   = S_SEQ * C_CH * FT;      // 524288
  float* sw     = base;
  float* lm     = sw + NMAP;
  float* alo    = lm + NMAP;
  float* ahi    = alo + NMAP;
  float* mask   = ahi + NMAP;
  float* rbuf   = mask + NMAP;
  float* scores = rbuf + NMAP;
  float* wcur   = scores + NMAP;
  float* wg     = wcur + NW;
  float* wgp    = wg + NW;                 // 3*NW
  float* nump   = wgp + 3 * NW;
  float* scal   = nump + S_SEQ;
  float* Sbuf   = scal + 8;                // 192*16*336
  ushort* wTb   = (ushort*)(Sbuf + (size_t)I_IMG * S_SEQ * 16 * SPL);
  ushort* featT = wTb + (size_t)S_SEQ * 16 * 512;
  ushort* featB = featT + (size_t)I_IMG * S_SEQ * HW * C_CH;

  convert_k<<<dim3(I_IMG * S_SEQ, 16), 256, 0, stream>>>(feat, featT, featB);
  prep_k<<<I_IMG * S_SEQ, 384, 0, stream>>>(bb, lblw, mskw, spw, lsl, freg,
                                            sw, lm, alo, ahi, scal);
  hipMemcpyAsync(wcur, w_in, (size_t)NW * sizeof(float),
                 hipMemcpyDeviceToDevice, stream);

  // initial scores via MFMA GEMM
  wT_k<<<S_SEQ, 256, 0, stream>>>(wcur, wTb);
  mfma_fwd_k<<<dim3(I_IMG * S_SEQ, 6), 256, 0, stream>>>(featT, wTb, Sbuf);
  combine0_k<<<I_IMG * S_SEQ, 384, 0, stream>>>(
      Sbuf, sw, lm, alo, ahi, scores, mask, rbuf);

  for (int it = 0; it < NITER; ++it) {
    mfma_tr_k<<<dim3(6, S_SEQ), 256, 0, stream>>>(featB, rbuf, wgp);
    combine_wg_k<<<S_SEQ, 256, 0, stream>>>(wgp, wcur, scal, wg, wTb, nump);
    mfma_fwd_k<<<dim3(I_IMG * S_SEQ, 6), 256, 0, stream>>>(featT, wTb, Sbuf);
    update_k<<<S_SEQ, 256, 0, stream>>>(
        wcur, wg, Sbuf, sw, lm, alo, ahi, scores, mask, rbuf, nump, scal);
  }
  hipMemcpyAsync(d_out, wcur, (size_t)NW * sizeof(float),
                 hipMemcpyDeviceToDevice, stream);
}